// Round 4
// baseline (1206.728 us; speedup 1.0000x reference)
//
#include <hip/hip_runtime.h>

#define ETOT 524288
#define SGR  1024
#define NPG  64
#define EPG  512
#define NFD  32
#define EFD  16
#define HCD  64

typedef unsigned uint2v __attribute__((ext_vector_type(2)));

__device__ __forceinline__ float elu_(float x){ return x>0.f ? x : (__expf(x)-1.f); }
__device__ __forceinline__ float sig_(float x){ return 1.f/(1.f+__expf(-x)); }
__device__ __forceinline__ float tanhf_(float x){ float e=__expf(2.f*x); return 1.f-2.f/(e+1.f); }
__device__ __forceinline__ float lrelu_(float x){ return x>0.f ? x : 0.2f*x; }

template<int C>
__device__ __forceinline__ float dppf(float v){
  return __int_as_float(__builtin_amdgcn_update_dpp(0, __float_as_int(v), C, 0xF, 0xF, true));
}

// sum over the 4 lanes of a quad, result in all 4 lanes — VALU DPP, no LDS pipe
__device__ __forceinline__ float quad_add(float v){
  v += dppf<0xB1>(v);   // [1,0,3,2]
  return v + dppf<0x4E>(v); // [2,3,0,1]
}

// Deterministic CSR build + per-dst mean edge_attr (self-loop fill).
// Called by all 512 threads; contains barriers.
__device__ void build_csr_la(int tid, int g, const int* ei, const float* ea,
                             int* s_edge, int* s_entry, int* s_off, int* s_deg,
                             float* s_la)
{
  const int base = g*NPG;
  const int* srcp = ei + (size_t)g*EPG;
  const int* dstp = ei + (size_t)ETOT + (size_t)g*EPG;
  for(int e=tid;e<EPG;e+=512)
    s_edge[e] = (srcp[e]-base) | ((dstp[e]-base)<<6);
  __syncthreads();
  if(tid<64){ int d=0;
    #pragma unroll 8
    for(int e=0;e<EPG;e++) d += (((s_edge[e]>>6)&63)==tid);
    s_deg[tid]=d; }
  __syncthreads();
  if(tid==0){ int a=0;
    for(int i=0;i<64;i++){ s_off[i]=a; a+=s_deg[i]; }
    s_off[64]=a; }
  __syncthreads();
  if(tid<64){ int pos=s_off[tid];
    for(int e=0;e<EPG;e++){ int en=s_edge[e];
      if(((en>>6)&63)==tid) s_entry[pos++] = (en&63) | (tid<<6) | (e<<12); } }
  __syncthreads();
  if(tid<256){ int n=tid>>2, f0=(tid&3)*4;
    float a0=0,a1=0,a2=0,a3=0;
    const int b=s_off[n], en=s_off[n+1];
    for(int p=b;p<en;p++){ int eid=s_entry[p]>>12;
      const float4 v = *(const float4*)(ea + ((size_t)g*EPG+(size_t)eid)*EFD + f0);
      a0+=v.x; a1+=v.y; a2+=v.z; a3+=v.w; }
    float inv = 1.f/fmaxf((float)(en-b),1.f);
    float4 r; r.x=a0*inv; r.y=a1*inv; r.z=a2*inv; r.w=a3*inv;
    *(float4*)(s_la + n*EFD + f0) = r; }
  __syncthreads();
}

// scores (576 = 512 edges + 64 self loops) + per-dst softmax; alpha left in s_sc.
__device__ void scores_softmax(int tid, int g, const float* ea,
   const int* s_entry, const int* s_off, const float* s_la,
   const float* s_We, const float* s_att, const float* s_xl, const float* s_xr,
   float* s_sc)
{
  for(int p=tid;p<576;p+=512){
    int src,dst; float eav[16];
    if(p<EPG){
      int en=s_entry[p]; src=en&63; dst=(en>>6)&63; int eid=en>>12;
      const float* epp = ea + ((size_t)g*EPG + (size_t)eid)*EFD;
      float4 v0=*(const float4*)(epp),   v1=*(const float4*)(epp+4);
      float4 v2=*(const float4*)(epp+8), v3=*(const float4*)(epp+12);
      eav[0]=v0.x;eav[1]=v0.y;eav[2]=v0.z;eav[3]=v0.w;
      eav[4]=v1.x;eav[5]=v1.y;eav[6]=v1.z;eav[7]=v1.w;
      eav[8]=v2.x;eav[9]=v2.y;eav[10]=v2.z;eav[11]=v2.w;
      eav[12]=v3.x;eav[13]=v3.y;eav[14]=v3.z;eav[15]=v3.w;
    } else {
      int n=p-EPG; src=n; dst=n;
      const float* epp = s_la + n*EFD;
      float4 v0=*(const float4*)(epp),   v1=*(const float4*)(epp+4);
      float4 v2=*(const float4*)(epp+8), v3=*(const float4*)(epp+12);
      eav[0]=v0.x;eav[1]=v0.y;eav[2]=v0.z;eav[3]=v0.w;
      eav[4]=v1.x;eav[5]=v1.y;eav[6]=v1.z;eav[7]=v1.w;
      eav[8]=v2.x;eav[9]=v2.y;eav[10]=v2.z;eav[11]=v2.w;
      eav[12]=v3.x;eav[13]=v3.y;eav[14]=v3.z;eav[15]=v3.w;
    }
    float score=0.f;
    #pragma unroll 4
    for(int cq=0;cq<16;cq++){
      float e0=0.f,e1=0.f,e2=0.f,e3=0.f;
      #pragma unroll
      for(int f=0;f<16;f++){
        const float4 wv=*(const float4*)(s_We + f*64 + cq*4);
        e0+=eav[f]*wv.x; e1+=eav[f]*wv.y; e2+=eav[f]*wv.z; e3+=eav[f]*wv.w;
      }
      const float4 xlv=*(const float4*)(s_xl + src*64 + ((cq^(src&15))<<2));
      const float4 xrv=*(const float4*)(s_xr + dst*64 + ((cq^(dst&15))<<2));
      const float4 av =*(const float4*)(s_att + cq*4);
      float m0=lrelu_(xlv.x+xrv.x+e0), m1=lrelu_(xlv.y+xrv.y+e1);
      float m2=lrelu_(xlv.z+xrv.z+e2), m3=lrelu_(xlv.w+xrv.w+e3);
      score += m0*av.x+m1*av.y+m2*av.z+m3*av.w;
    }
    s_sc[p]=score;
  }
  __syncthreads();
  if(tid<64){
    const int b=s_off[tid], e=s_off[tid+1];
    float mx=s_sc[EPG+tid];
    for(int p=b;p<e;p++) mx=fmaxf(mx,s_sc[p]);
    float v=__expf(s_sc[EPG+tid]-mx); float den=v; s_sc[EPG+tid]=v;
    for(int p=b;p<e;p++){ float w=__expf(s_sc[p]-mx); s_sc[p]=w; den+=w; }
    const float inv=1.f/(den+1e-16f);
    s_sc[EPG+tid]*=inv;
    for(int p=b;p<e;p++) s_sc[p]*=inv;
  }
  __syncthreads();
}

__global__ __launch_bounds__(512,4) void gat1_k(
    const float* __restrict__ x, const int* __restrict__ ei,
    const float* __restrict__ ea, const float* __restrict__ Wl,
    const float* __restrict__ bl, const float* __restrict__ Wr,
    const float* __restrict__ br, const float* __restrict__ We,
    const float* __restrict__ att, const float* __restrict__ bias,
    float* __restrict__ h1)
{
  const int g = blockIdx.x, tid = threadIdx.x;
  const int base = g*NPG;

  __shared__ __align__(16) float s_x[NPG*36];
  __shared__ __align__(16) float s_xl[NPG*64];
  __shared__ __align__(16) float s_xr[NPG*64];
  __shared__ __align__(16) float s_W[2*32*64];
  __shared__ __align__(16) float s_We[16*64];
  __shared__ __align__(16) float s_att[64];
  __shared__ __align__(16) float s_la[NPG*EFD];
  __shared__ float s_sc[576];
  __shared__ int   s_edge[EPG];
  __shared__ int   s_entry[EPG];
  __shared__ int   s_off[65];
  __shared__ int   s_deg[64];

  // stage x tile [64][32] (padded stride 36)
  { int n=tid>>3, kq=tid&7;
    float4 v = *(const float4*)(x + (size_t)(base+n)*NFD + kq*4);
    *(float4*)(s_x + n*36 + kq*4) = v; }

  build_csr_la(tid, g, ei, ea, s_edge, s_entry, s_off, s_deg, s_la);

  for(int h=0;h<3;h++){
    // stage weight slices for this head
    { int k=tid>>4, c0=(tid&15)*4;
      *(float4*)(s_W + k*64 + c0)        = *(const float4*)(Wl + (size_t)k*192 + h*64 + c0);
      *(float4*)(s_W + 2048 + k*64 + c0) = *(const float4*)(Wr + (size_t)k*192 + h*64 + c0); }
    if(tid<256){ int f=tid>>4, c0=(tid&15)*4;
      *(float4*)(s_We + f*64 + c0) = *(const float4*)(We + (size_t)f*192 + h*64 + c0); }
    if(tid<16) *(float4*)(s_att + tid*4) = *(const float4*)(att + h*64 + tid*4);
    __syncthreads();

    // GEMM: xl = x@Wl_h + bl_h ; xr = x@Wr_h + br_h  (64x32 @ 32x64)
    { const int cg=tid&15, ng=tid>>4, n0=ng*2, c0=cg*4;
      const float4 blv=*(const float4*)(bl + h*64 + c0);
      const float4 brv=*(const float4*)(br + h*64 + c0);
      float accl[2][4]={{blv.x,blv.y,blv.z,blv.w},{blv.x,blv.y,blv.z,blv.w}};
      float accr[2][4]={{brv.x,brv.y,brv.z,brv.w},{brv.x,brv.y,brv.z,brv.w}};
      #pragma unroll
      for(int kq=0;kq<8;kq++){
        float xs0[4], xs1[4];
        { float4 v=*(const float4*)(s_x + n0*36 + kq*4);     xs0[0]=v.x;xs0[1]=v.y;xs0[2]=v.z;xs0[3]=v.w; }
        { float4 v=*(const float4*)(s_x + (n0+1)*36 + kq*4); xs1[0]=v.x;xs1[1]=v.y;xs1[2]=v.z;xs1[3]=v.w; }
        #pragma unroll
        for(int f=0;f<4;f++){
          const float4 wl=*(const float4*)(s_W + (kq*4+f)*64 + c0);
          const float4 wr=*(const float4*)(s_W + 2048 + (kq*4+f)*64 + c0);
          accl[0][0]+=xs0[f]*wl.x; accl[0][1]+=xs0[f]*wl.y; accl[0][2]+=xs0[f]*wl.z; accl[0][3]+=xs0[f]*wl.w;
          accl[1][0]+=xs1[f]*wl.x; accl[1][1]+=xs1[f]*wl.y; accl[1][2]+=xs1[f]*wl.z; accl[1][3]+=xs1[f]*wl.w;
          accr[0][0]+=xs0[f]*wr.x; accr[0][1]+=xs0[f]*wr.y; accr[0][2]+=xs0[f]*wr.z; accr[0][3]+=xs0[f]*wr.w;
          accr[1][0]+=xs1[f]*wr.x; accr[1][1]+=xs1[f]*wr.y; accr[1][2]+=xs1[f]*wr.z; accr[1][3]+=xs1[f]*wr.w;
        }
      }
      #pragma unroll
      for(int i=0;i<2;i++){
        const int n=n0+i, sq=((cg^(n&15))<<2);
        float4 vl; vl.x=accl[i][0]; vl.y=accl[i][1]; vl.z=accl[i][2]; vl.w=accl[i][3];
        float4 vr; vr.x=accr[i][0]; vr.y=accr[i][1]; vr.z=accr[i][2]; vr.w=accr[i][3];
        *(float4*)(s_xl + n*64 + sq)=vl;
        *(float4*)(s_xr + n*64 + sq)=vr;
      }
    }
    __syncthreads();

    scores_softmax(tid, g, ea, s_entry, s_off, s_la, s_We, s_att, s_xl, s_xr, s_sc);

    // aggregate alpha * xl[src] per (dst, 8-channel slice) + bias + ELU -> h1
    { const int n=tid>>3, c0a=(tid&7)*8;
      float acc[8]={0.f,0.f,0.f,0.f,0.f,0.f,0.f,0.f};
      const int b=s_off[n], e=s_off[n+1];
      for(int p=b;p<e;p++){
        const int en=s_entry[p], src=en&63;
        const float a=s_sc[p];
        #pragma unroll
        for(int qq=0;qq<2;qq++){
          const int cq=(c0a>>2)+qq;
          const float4 xv=*(const float4*)(s_xl + src*64 + ((cq^(src&15))<<2));
          acc[qq*4+0]+=a*xv.x; acc[qq*4+1]+=a*xv.y; acc[qq*4+2]+=a*xv.z; acc[qq*4+3]+=a*xv.w;
        }
      }
      { const float a=s_sc[EPG+n];
        #pragma unroll
        for(int qq=0;qq<2;qq++){
          const int cq=(c0a>>2)+qq;
          const float4 xv=*(const float4*)(s_xl + n*64 + ((cq^(n&15))<<2));
          acc[qq*4+0]+=a*xv.x; acc[qq*4+1]+=a*xv.y; acc[qq*4+2]+=a*xv.z; acc[qq*4+3]+=a*xv.w;
        } }
      float* op = h1 + (size_t)(base+n)*192 + h*64 + c0a;
      #pragma unroll
      for(int qq=0;qq<2;qq++){
        const float4 bv=*(const float4*)(bias + h*64 + c0a + qq*4);
        float4 r; r.x=elu_(acc[qq*4+0]+bv.x); r.y=elu_(acc[qq*4+1]+bv.y);
                  r.z=elu_(acc[qq*4+2]+bv.z); r.w=elu_(acc[qq*4+3]+bv.w);
        *(float4*)(op + qq*4)=r;
      }
    }
    __syncthreads();
  }
}

__global__ __launch_bounds__(512,4) void gat2_k(
    const float* __restrict__ h1, const int* __restrict__ ei,
    const float* __restrict__ ea, const float* __restrict__ Wl,
    const float* __restrict__ bl, const float* __restrict__ Wr,
    const float* __restrict__ br, const float* __restrict__ We,
    const float* __restrict__ att, const float* __restrict__ bias,
    const float* __restrict__ Wih, const float* __restrict__ bih,
    const float* __restrict__ bhh, float* __restrict__ xproj)
{
  const int g = blockIdx.x, tid = threadIdx.x;
  const int base = g*NPG;

  __shared__ __align__(16) float s_hx[NPG*36];
  __shared__ __align__(16) float s_xl[NPG*64];
  __shared__ __align__(16) float s_xr[NPG*64];
  __shared__ __align__(16) float s_W[2*32*64];   // also reused as s_out (64x64)
  __shared__ __align__(16) float s_We[16*64];
  __shared__ __align__(16) float s_att[64];
  __shared__ __align__(16) float s_la[NPG*EFD];
  __shared__ float s_sc[576];
  __shared__ float s_pool[64];
  __shared__ int   s_edge[EPG];
  __shared__ int   s_entry[EPG];
  __shared__ int   s_off[65];
  __shared__ int   s_deg[64];
  float* s_out = s_W;

  build_csr_la(tid, g, ei, ea, s_edge, s_entry, s_off, s_deg, s_la);

  // GEMM: xl/xr = h1 @ Wl2/Wr2 + b  (64x192 @ 192x64, 6 K-chunks of 32)
  const int cg=tid&15, ng=tid>>4, n0=ng*2, gc0=cg*4;
  float accl[2][4], accr[2][4];
  { const float4 blv=*(const float4*)(bl + gc0);
    const float4 brv=*(const float4*)(br + gc0);
    #pragma unroll
    for(int i=0;i<2;i++){
      accl[i][0]=blv.x; accl[i][1]=blv.y; accl[i][2]=blv.z; accl[i][3]=blv.w;
      accr[i][0]=brv.x; accr[i][1]=brv.y; accr[i][2]=brv.z; accr[i][3]=brv.w; } }
  for(int kc=0;kc<6;kc++){
    { int n=tid>>3, kq=tid&7;
      *(float4*)(s_hx + n*36 + kq*4) = *(const float4*)(h1 + (size_t)(base+n)*192 + kc*32 + kq*4); }
    { int k=tid>>4, cc=(tid&15)*4;
      *(float4*)(s_W + k*64 + cc)        = *(const float4*)(Wl + (size_t)(kc*32+k)*64 + cc);
      *(float4*)(s_W + 2048 + k*64 + cc) = *(const float4*)(Wr + (size_t)(kc*32+k)*64 + cc); }
    __syncthreads();
    #pragma unroll
    for(int kq=0;kq<8;kq++){
      float xs0[4], xs1[4];
      { float4 v=*(const float4*)(s_hx + n0*36 + kq*4);     xs0[0]=v.x;xs0[1]=v.y;xs0[2]=v.z;xs0[3]=v.w; }
      { float4 v=*(const float4*)(s_hx + (n0+1)*36 + kq*4); xs1[0]=v.x;xs1[1]=v.y;xs1[2]=v.z;xs1[3]=v.w; }
      #pragma unroll
      for(int f=0;f<4;f++){
        const float4 wl=*(const float4*)(s_W + (kq*4+f)*64 + gc0);
        const float4 wr=*(const float4*)(s_W + 2048 + (kq*4+f)*64 + gc0);
        accl[0][0]+=xs0[f]*wl.x; accl[0][1]+=xs0[f]*wl.y; accl[0][2]+=xs0[f]*wl.z; accl[0][3]+=xs0[f]*wl.w;
        accl[1][0]+=xs1[f]*wl.x; accl[1][1]+=xs1[f]*wl.y; accl[1][2]+=xs1[f]*wl.z; accl[1][3]+=xs1[f]*wl.w;
        accr[0][0]+=xs0[f]*wr.x; accr[0][1]+=xs0[f]*wr.y; accr[0][2]+=xs0[f]*wr.z; accr[0][3]+=xs0[f]*wr.w;
        accr[1][0]+=xs1[f]*wr.x; accr[1][1]+=xs1[f]*wr.y; accr[1][2]+=xs1[f]*wr.z; accr[1][3]+=xs1[f]*wr.w;
      }
    }
    __syncthreads();
  }
  // write xl/xr (swizzled) and stage We2/att2
  #pragma unroll
  for(int i=0;i<2;i++){
    const int n=n0+i, sq=((cg^(n&15))<<2);
    float4 vl; vl.x=accl[i][0]; vl.y=accl[i][1]; vl.z=accl[i][2]; vl.w=accl[i][3];
    float4 vr; vr.x=accr[i][0]; vr.y=accr[i][1]; vr.z=accr[i][2]; vr.w=accr[i][3];
    *(float4*)(s_xl + n*64 + sq)=vl;
    *(float4*)(s_xr + n*64 + sq)=vr;
  }
  if(tid<256){ int f=tid>>4, cc=(tid&15)*4;
    *(float4*)(s_We + f*64 + cc) = *(const float4*)(We + (size_t)f*64 + cc); }
  if(tid<16) *(float4*)(s_att + tid*4) = *(const float4*)(att + tid*4);
  __syncthreads();

  scores_softmax(tid, g, ea, s_entry, s_off, s_la, s_We, s_att, s_xl, s_xr, s_sc);

  // aggregate + bias + ELU into s_out (aliases s_W; GEMM done)
  { const int n=tid>>3, c0a=(tid&7)*8;
    float acc[8]={0.f,0.f,0.f,0.f,0.f,0.f,0.f,0.f};
    const int b=s_off[n], e=s_off[n+1];
    for(int p=b;p<e;p++){
      const int en=s_entry[p], src=en&63;
      const float a=s_sc[p];
      #pragma unroll
      for(int qq=0;qq<2;qq++){
        const int cq=(c0a>>2)+qq;
        const float4 xv=*(const float4*)(s_xl + src*64 + ((cq^(src&15))<<2));
        acc[qq*4+0]+=a*xv.x; acc[qq*4+1]+=a*xv.y; acc[qq*4+2]+=a*xv.z; acc[qq*4+3]+=a*xv.w;
      }
    }
    { const float a=s_sc[EPG+n];
      #pragma unroll
      for(int qq=0;qq<2;qq++){
        const int cq=(c0a>>2)+qq;
        const float4 xv=*(const float4*)(s_xl + n*64 + ((cq^(n&15))<<2));
        acc[qq*4+0]+=a*xv.x; acc[qq*4+1]+=a*xv.y; acc[qq*4+2]+=a*xv.z; acc[qq*4+3]+=a*xv.w;
      } }
    #pragma unroll
    for(int qq=0;qq<2;qq++){
      const float4 bv=*(const float4*)(bias + c0a + qq*4);
      float4 r; r.x=elu_(acc[qq*4+0]+bv.x); r.y=elu_(acc[qq*4+1]+bv.y);
                r.z=elu_(acc[qq*4+2]+bv.z); r.w=elu_(acc[qq*4+3]+bv.w);
      *(float4*)(s_out + n*64 + c0a + qq*4)=r;
    }
  }
  __syncthreads();
  // mean-pool over the 64 nodes
  if(tid<64){ float s=0.f;
    #pragma unroll 8
    for(int n2=0;n2<64;n2++) s += s_out[n2*64+tid];
    s_pool[tid]=s*(1.f/64.f); }
  __syncthreads();
  // LSTM input projection for this timestep: xproj[g][r] = bih[r]+bhh[r]+Wih[r]·pooled
  if(tid<256){
    float a=bih[tid]+bhh[tid];
    #pragma unroll
    for(int kq=0;kq<16;kq++){
      const float4 w=*(const float4*)(Wih + (size_t)tid*64 + kq*4);
      a += w.x*s_pool[kq*4+0] + w.y*s_pool[kq*4+1] + w.z*s_pool[kq*4+2] + w.w*s_pool[kq*4+3];
    }
    xproj[(size_t)g*256 + tid]=a;
  }
}

// LSTM: 512 threads, 32 weights/lane (residency by construction).
// lane bits: [1:0]=gate m, [3:2]|[5]=node-in-wave ln, [4]=k-half kh.
// k-half sum: v_permlane16_swap (VALU). gate all-gather: 3 quad_perm DPPs + cndmasks.
// One barrier per step; c replicated in all 8 lanes of a node.
__global__ __launch_bounds__(512,2) void lstm_k(
    const float* __restrict__ xproj, const float* __restrict__ Whh,
    const float* __restrict__ W1, const float* __restrict__ b1,
    const float* __restrict__ W2, const float* __restrict__ b2,
    float* __restrict__ out)
{
  const int tid=threadIdx.x;
  const int lane=tid&63, wv=tid>>6;
  const int m=lane&3, kh=(lane>>4)&1;
  const int ln=((lane>>2)&3)|(((lane>>5)&1)<<2);
  const int l=wv*8+ln;
  const int r=m*64+l;
  __shared__ __align__(16) float s_h[2][64];
  __shared__ float s_y[32];
  float w[32];
  { const float* wp = Whh + (size_t)r*64 + kh*32;
    #pragma unroll
    for(int j=0;j<8;j++){
      const float4 v=*(const float4*)(wp + j*4);
      w[j*4]=v.x; w[j*4+1]=v.y; w[j*4+2]=v.z; w[j*4+3]=v.w;
    }
  }
  #pragma unroll
  for(int i=0;i<32;i++) asm volatile("" : "+v"(w[i]));

  float c=0.f;
  float xp = xproj[m*64+l];
  if(tid<64){ s_h[0][tid]=0.f; s_h[1][tid]=0.f; }
  __syncthreads();
  const bool mb0 = (m&1)!=0, mb1 = (m&2)!=0;
  const bool writer = ((lane & 0x13) == 0);  // m==0 && kh==0
  int cur=0;
  for(int t=0;t<1024;t++){
    float hb[32];
    #pragma unroll
    for(int j=0;j<8;j++){
      const float4 v=*(const float4*)(&s_h[cur][kh*32 + j*4]);
      hb[j*4]=v.x; hb[j*4+1]=v.y; hb[j*4+2]=v.z; hb[j*4+3]=v.w;
    }
    float xn=0.f;
    if(t<1023) xn = xproj[(size_t)(t+1)*256 + m*64 + l];
    float pa=0.f,pb=0.f;
    #pragma unroll
    for(int k=0;k<16;k++){ pa+=w[k]*hb[k]; pb+=w[16+k]*hb[16+k]; }
    float p = pa+pb + (kh ? 0.f : xp);   // add xproj once (kh=0 lane only)
    // k-half pair sum over lane^16
    float a;
#if __has_builtin(__builtin_amdgcn_permlane16_swap)
    { uint2v rr = __builtin_amdgcn_permlane16_swap(__float_as_uint(p), __float_as_uint(p), false, false);
      a = __uint_as_float(rr.x) + __uint_as_float(rr.y); }
#else
    a = p + __int_as_float(__builtin_amdgcn_ds_swizzle(__float_as_int(p), 0x401F));
#endif
    // gather the 4 gate pre-activations across the quad
    const float b1v = dppf<0xB1>(a);   // from m^1
    const float b2v = dppf<0x4E>(a);   // from m^2
    const float b3v = dppf<0x1B>(a);   // from m^3
    const float t0 = mb0 ? b1v : a;
    const float t1 = mb0 ? a   : b1v;
    const float t2 = mb0 ? b3v : b2v;
    const float t3 = mb0 ? b2v : b3v;
    const float gi = mb1 ? t2 : t0;
    const float gf = mb1 ? t3 : t1;
    const float gg = mb1 ? t0 : t2;
    const float go = mb1 ? t1 : t3;
    c = sig_(gf)*c + sig_(gi)*tanhf_(gg);
    const float hn = sig_(go)*tanhf_(c);
    if(writer) s_h[cur^1][l]=hn;
    xp=xn;
    cur^=1;
    __syncthreads();
  }
  // MLP head: relu(h@W1+b1)@W2+b2  (final h is in s_h[cur])
  if(tid<32){
    float a=b1[tid];
    #pragma unroll 8
    for(int k=0;k<64;k++) a += s_h[cur][k]*W1[k*32+tid];
    s_y[tid]=fmaxf(a,0.f);
  }
  __syncthreads();
  if(tid==0){
    float a=b2[0];
    #pragma unroll
    for(int j=0;j<32;j++) a += s_y[j]*W2[j];
    out[0]=a;
  }
}

extern "C" void kernel_launch(void* const* d_in, const int* in_sizes, int n_in,
                              void* d_out, int out_size, void* d_ws, size_t ws_size,
                              hipStream_t stream) {
  (void)in_sizes; (void)n_in; (void)out_size; (void)ws_size;
  const float* x    = (const float*)d_in[0];
  const int*   ei   = (const int*)d_in[1];
  const float* ea   = (const float*)d_in[2];
  const float* Wl1  = (const float*)d_in[4];
  const float* bl1  = (const float*)d_in[5];
  const float* Wr1  = (const float*)d_in[6];
  const float* br1  = (const float*)d_in[7];
  const float* We1  = (const float*)d_in[8];
  const float* att1 = (const float*)d_in[9];
  const float* bias1= (const float*)d_in[10];
  const float* Wl2  = (const float*)d_in[11];
  const float* bl2  = (const float*)d_in[12];
  const float* Wr2  = (const float*)d_in[13];
  const float* br2  = (const float*)d_in[14];
  const float* We2  = (const float*)d_in[15];
  const float* att2 = (const float*)d_in[16];
  const float* bias2= (const float*)d_in[17];
  const float* Wih  = (const float*)d_in[18];
  const float* Whh  = (const float*)d_in[19];
  const float* bih  = (const float*)d_in[20];
  const float* bhh  = (const float*)d_in[21];
  const float* W1   = (const float*)d_in[22];
  const float* b1   = (const float*)d_in[23];
  const float* W2   = (const float*)d_in[24];
  const float* b2   = (const float*)d_in[25];

  float* h1w = (float*)d_ws;                                  // 65536*192*4 = 50331648 B
  float* xpw = (float*)((char*)d_ws + (size_t)50331648);      // 1024*256*4  = 1048576 B
  float* outp = (float*)d_out;

  gat1_k<<<dim3(SGR), dim3(512), 0, stream>>>(x, ei, ea, Wl1, bl1, Wr1, br1, We1, att1, bias1, h1w);
  gat2_k<<<dim3(SGR), dim3(512), 0, stream>>>(h1w, ei, ea, Wl2, bl2, Wr2, br2, We2, att2, bias2,
                                              Wih, bih, bhh, xpw);
  lstm_k<<<dim3(1), dim3(512), 0, stream>>>(xpw, Whh, W1, b1, W2, b2, outp);
}

// Round 6
// 904.407 us; speedup vs baseline: 1.3343x; 1.3343x over previous
//
#include <hip/hip_runtime.h>

#define ETOT 524288
#define SGR  1024
#define NPG  64
#define EPG  512
#define NFD  32
#define EFD  16
#define HCD  64

__device__ __forceinline__ float elu_(float x){ return x>0.f ? x : (__expf(x)-1.f); }
__device__ __forceinline__ float sig_(float x){ return 1.f/(1.f+__expf(-x)); }
__device__ __forceinline__ float tanhf_(float x){ float e=__expf(2.f*x); return 1.f-2.f/(e+1.f); }
__device__ __forceinline__ float lrelu_(float x){ return x>0.f ? x : 0.2f*x; }

template<int C>
__device__ __forceinline__ float dppf(float v){
  return __int_as_float(__builtin_amdgcn_update_dpp(0, __float_as_int(v), C, 0xF, 0xF, true));
}

// sum over the 4 lanes of a quad, result in all 4 lanes — VALU DPP, no LDS pipe
__device__ __forceinline__ float quad_add(float v){
  v += dppf<0xB1>(v);       // [1,0,3,2]
  return v + dppf<0x4E>(v); // [2,3,0,1]
}

// Deterministic CSR build + per-dst mean edge_attr (self-loop fill).
// Called by all 512 threads; contains barriers.
__device__ void build_csr_la(int tid, int g, const int* ei, const float* ea,
                             int* s_edge, int* s_entry, int* s_off, int* s_deg,
                             float* s_la)
{
  const int base = g*NPG;
  const int* srcp = ei + (size_t)g*EPG;
  const int* dstp = ei + (size_t)ETOT + (size_t)g*EPG;
  for(int e=tid;e<EPG;e+=512)
    s_edge[e] = (srcp[e]-base) | ((dstp[e]-base)<<6);
  __syncthreads();
  if(tid<64){ int d=0;
    #pragma unroll 8
    for(int e=0;e<EPG;e++) d += (((s_edge[e]>>6)&63)==tid);
    s_deg[tid]=d; }
  __syncthreads();
  if(tid==0){ int a=0;
    for(int i=0;i<64;i++){ s_off[i]=a; a+=s_deg[i]; }
    s_off[64]=a; }
  __syncthreads();
  if(tid<64){ int pos=s_off[tid];
    for(int e=0;e<EPG;e++){ int en=s_edge[e];
      if(((en>>6)&63)==tid) s_entry[pos++] = (en&63) | (tid<<6) | (e<<12); } }
  __syncthreads();
  if(tid<256){ int n=tid>>2, f0=(tid&3)*4;
    float a0=0,a1=0,a2=0,a3=0;
    const int b=s_off[n], en=s_off[n+1];
    for(int p=b;p<en;p++){ int eid=s_entry[p]>>12;
      const float4 v = *(const float4*)(ea + ((size_t)g*EPG+(size_t)eid)*EFD + f0);
      a0+=v.x; a1+=v.y; a2+=v.z; a3+=v.w; }
    float inv = 1.f/fmaxf((float)(en-b),1.f);
    float4 r; r.x=a0*inv; r.y=a1*inv; r.z=a2*inv; r.w=a3*inv;
    *(float4*)(s_la + n*EFD + f0) = r; }
  __syncthreads();
}

// scores (576 = 512 edges + 64 self loops) + per-dst softmax; alpha left in s_sc.
__device__ void scores_softmax(int tid, int g, const float* ea,
   const int* s_entry, const int* s_off, const float* s_la,
   const float* s_We, const float* s_att, const float* s_xl, const float* s_xr,
   float* s_sc)
{
  for(int p=tid;p<576;p+=512){
    int src,dst; float eav[16];
    if(p<EPG){
      int en=s_entry[p]; src=en&63; dst=(en>>6)&63; int eid=en>>12;
      const float* epp = ea + ((size_t)g*EPG + (size_t)eid)*EFD;
      float4 v0=*(const float4*)(epp),   v1=*(const float4*)(epp+4);
      float4 v2=*(const float4*)(epp+8), v3=*(const float4*)(epp+12);
      eav[0]=v0.x;eav[1]=v0.y;eav[2]=v0.z;eav[3]=v0.w;
      eav[4]=v1.x;eav[5]=v1.y;eav[6]=v1.z;eav[7]=v1.w;
      eav[8]=v2.x;eav[9]=v2.y;eav[10]=v2.z;eav[11]=v2.w;
      eav[12]=v3.x;eav[13]=v3.y;eav[14]=v3.z;eav[15]=v3.w;
    } else {
      int n=p-EPG; src=n; dst=n;
      const float* epp = s_la + n*EFD;
      float4 v0=*(const float4*)(epp),   v1=*(const float4*)(epp+4);
      float4 v2=*(const float4*)(epp+8), v3=*(const float4*)(epp+12);
      eav[0]=v0.x;eav[1]=v0.y;eav[2]=v0.z;eav[3]=v0.w;
      eav[4]=v1.x;eav[5]=v1.y;eav[6]=v1.z;eav[7]=v1.w;
      eav[8]=v2.x;eav[9]=v2.y;eav[10]=v2.z;eav[11]=v2.w;
      eav[12]=v3.x;eav[13]=v3.y;eav[14]=v3.z;eav[15]=v3.w;
    }
    float score=0.f;
    #pragma unroll 4
    for(int cq=0;cq<16;cq++){
      float e0=0.f,e1=0.f,e2=0.f,e3=0.f;
      #pragma unroll
      for(int f=0;f<16;f++){
        const float4 wv=*(const float4*)(s_We + f*64 + cq*4);
        e0+=eav[f]*wv.x; e1+=eav[f]*wv.y; e2+=eav[f]*wv.z; e3+=eav[f]*wv.w;
      }
      const float4 xlv=*(const float4*)(s_xl + src*64 + ((cq^(src&15))<<2));
      const float4 xrv=*(const float4*)(s_xr + dst*64 + ((cq^(dst&15))<<2));
      const float4 av =*(const float4*)(s_att + cq*4);
      float m0=lrelu_(xlv.x+xrv.x+e0), m1=lrelu_(xlv.y+xrv.y+e1);
      float m2=lrelu_(xlv.z+xrv.z+e2), m3=lrelu_(xlv.w+xrv.w+e3);
      score += m0*av.x+m1*av.y+m2*av.z+m3*av.w;
    }
    s_sc[p]=score;
  }
  __syncthreads();
  if(tid<64){
    const int b=s_off[tid], e=s_off[tid+1];
    float mx=s_sc[EPG+tid];
    for(int p=b;p<e;p++) mx=fmaxf(mx,s_sc[p]);
    float v=__expf(s_sc[EPG+tid]-mx); float den=v; s_sc[EPG+tid]=v;
    for(int p=b;p<e;p++){ float w=__expf(s_sc[p]-mx); s_sc[p]=w; den+=w; }
    const float inv=1.f/(den+1e-16f);
    s_sc[EPG+tid]*=inv;
    for(int p=b;p<e;p++) s_sc[p]*=inv;
  }
  __syncthreads();
}

__global__ __launch_bounds__(512,4) void gat1_k(
    const float* __restrict__ x, const int* __restrict__ ei,
    const float* __restrict__ ea, const float* __restrict__ Wl,
    const float* __restrict__ bl, const float* __restrict__ Wr,
    const float* __restrict__ br, const float* __restrict__ We,
    const float* __restrict__ att, const float* __restrict__ bias,
    float* __restrict__ h1)
{
  const int g = blockIdx.x, tid = threadIdx.x;
  const int base = g*NPG;

  __shared__ __align__(16) float s_x[NPG*36];
  __shared__ __align__(16) float s_xl[NPG*64];
  __shared__ __align__(16) float s_xr[NPG*64];
  __shared__ __align__(16) float s_W[2*32*64];
  __shared__ __align__(16) float s_We[16*64];
  __shared__ __align__(16) float s_att[64];
  __shared__ __align__(16) float s_la[NPG*EFD];
  __shared__ float s_sc[576];
  __shared__ int   s_edge[EPG];
  __shared__ int   s_entry[EPG];
  __shared__ int   s_off[65];
  __shared__ int   s_deg[64];

  // stage x tile [64][32] (padded stride 36)
  { int n=tid>>3, kq=tid&7;
    float4 v = *(const float4*)(x + (size_t)(base+n)*NFD + kq*4);
    *(float4*)(s_x + n*36 + kq*4) = v; }

  build_csr_la(tid, g, ei, ea, s_edge, s_entry, s_off, s_deg, s_la);

  for(int h=0;h<3;h++){
    // stage weight slices for this head
    { int k=tid>>4, c0=(tid&15)*4;
      *(float4*)(s_W + k*64 + c0)        = *(const float4*)(Wl + (size_t)k*192 + h*64 + c0);
      *(float4*)(s_W + 2048 + k*64 + c0) = *(const float4*)(Wr + (size_t)k*192 + h*64 + c0); }
    if(tid<256){ int f=tid>>4, c0=(tid&15)*4;
      *(float4*)(s_We + f*64 + c0) = *(const float4*)(We + (size_t)f*192 + h*64 + c0); }
    if(tid<16) *(float4*)(s_att + tid*4) = *(const float4*)(att + h*64 + tid*4);
    __syncthreads();

    // GEMM: xl = x@Wl_h + bl_h ; xr = x@Wr_h + br_h  (64x32 @ 32x64)
    { const int cg=tid&15, ng=tid>>4, n0=ng*2, c0=cg*4;
      const float4 blv=*(const float4*)(bl + h*64 + c0);
      const float4 brv=*(const float4*)(br + h*64 + c0);
      float accl[2][4]={{blv.x,blv.y,blv.z,blv.w},{blv.x,blv.y,blv.z,blv.w}};
      float accr[2][4]={{brv.x,brv.y,brv.z,brv.w},{brv.x,brv.y,brv.z,brv.w}};
      #pragma unroll
      for(int kq=0;kq<8;kq++){
        float xs0[4], xs1[4];
        { float4 v=*(const float4*)(s_x + n0*36 + kq*4);     xs0[0]=v.x;xs0[1]=v.y;xs0[2]=v.z;xs0[3]=v.w; }
        { float4 v=*(const float4*)(s_x + (n0+1)*36 + kq*4); xs1[0]=v.x;xs1[1]=v.y;xs1[2]=v.z;xs1[3]=v.w; }
        #pragma unroll
        for(int f=0;f<4;f++){
          const float4 wl=*(const float4*)(s_W + (kq*4+f)*64 + c0);
          const float4 wr=*(const float4*)(s_W + 2048 + (kq*4+f)*64 + c0);
          accl[0][0]+=xs0[f]*wl.x; accl[0][1]+=xs0[f]*wl.y; accl[0][2]+=xs0[f]*wl.z; accl[0][3]+=xs0[f]*wl.w;
          accl[1][0]+=xs1[f]*wl.x; accl[1][1]+=xs1[f]*wl.y; accl[1][2]+=xs1[f]*wl.z; accl[1][3]+=xs1[f]*wl.w;
          accr[0][0]+=xs0[f]*wr.x; accr[0][1]+=xs0[f]*wr.y; accr[0][2]+=xs0[f]*wr.z; accr[0][3]+=xs0[f]*wr.w;
          accr[1][0]+=xs1[f]*wr.x; accr[1][1]+=xs1[f]*wr.y; accr[1][2]+=xs1[f]*wr.z; accr[1][3]+=xs1[f]*wr.w;
        }
      }
      #pragma unroll
      for(int i=0;i<2;i++){
        const int n=n0+i, sq=((cg^(n&15))<<2);
        float4 vl; vl.x=accl[i][0]; vl.y=accl[i][1]; vl.z=accl[i][2]; vl.w=accl[i][3];
        float4 vr; vr.x=accr[i][0]; vr.y=accr[i][1]; vr.z=accr[i][2]; vr.w=accr[i][3];
        *(float4*)(s_xl + n*64 + sq)=vl;
        *(float4*)(s_xr + n*64 + sq)=vr;
      }
    }
    __syncthreads();

    scores_softmax(tid, g, ea, s_entry, s_off, s_la, s_We, s_att, s_xl, s_xr, s_sc);

    // aggregate alpha * xl[src] per (dst, 8-channel slice) + bias + ELU -> h1
    { const int n=tid>>3, c0a=(tid&7)*8;
      float acc[8]={0.f,0.f,0.f,0.f,0.f,0.f,0.f,0.f};
      const int b=s_off[n], e=s_off[n+1];
      for(int p=b;p<e;p++){
        const int en=s_entry[p], src=en&63;
        const float a=s_sc[p];
        #pragma unroll
        for(int qq=0;qq<2;qq++){
          const int cq=(c0a>>2)+qq;
          const float4 xv=*(const float4*)(s_xl + src*64 + ((cq^(src&15))<<2));
          acc[qq*4+0]+=a*xv.x; acc[qq*4+1]+=a*xv.y; acc[qq*4+2]+=a*xv.z; acc[qq*4+3]+=a*xv.w;
        }
      }
      { const float a=s_sc[EPG+n];
        #pragma unroll
        for(int qq=0;qq<2;qq++){
          const int cq=(c0a>>2)+qq;
          const float4 xv=*(const float4*)(s_xl + n*64 + ((cq^(n&15))<<2));
          acc[qq*4+0]+=a*xv.x; acc[qq*4+1]+=a*xv.y; acc[qq*4+2]+=a*xv.z; acc[qq*4+3]+=a*xv.w;
        } }
      float* op = h1 + (size_t)(base+n)*192 + h*64 + c0a;
      #pragma unroll
      for(int qq=0;qq<2;qq++){
        const float4 bv=*(const float4*)(bias + h*64 + c0a + qq*4);
        float4 r; r.x=elu_(acc[qq*4+0]+bv.x); r.y=elu_(acc[qq*4+1]+bv.y);
                  r.z=elu_(acc[qq*4+2]+bv.z); r.w=elu_(acc[qq*4+3]+bv.w);
        *(float4*)(op + qq*4)=r;
      }
    }
    __syncthreads();
  }
}

__global__ __launch_bounds__(512,4) void gat2_k(
    const float* __restrict__ h1, const int* __restrict__ ei,
    const float* __restrict__ ea, const float* __restrict__ Wl,
    const float* __restrict__ bl, const float* __restrict__ Wr,
    const float* __restrict__ br, const float* __restrict__ We,
    const float* __restrict__ att, const float* __restrict__ bias,
    const float* __restrict__ Wih, const float* __restrict__ bih,
    const float* __restrict__ bhh, float* __restrict__ xproj)
{
  const int g = blockIdx.x, tid = threadIdx.x;
  const int base = g*NPG;

  __shared__ __align__(16) float s_hx[NPG*36];
  __shared__ __align__(16) float s_xl[NPG*64];
  __shared__ __align__(16) float s_xr[NPG*64];
  __shared__ __align__(16) float s_W[2*32*64];   // also reused as s_out (64x64)
  __shared__ __align__(16) float s_We[16*64];
  __shared__ __align__(16) float s_att[64];
  __shared__ __align__(16) float s_la[NPG*EFD];
  __shared__ float s_sc[576];
  __shared__ float s_pool[64];
  __shared__ int   s_edge[EPG];
  __shared__ int   s_entry[EPG];
  __shared__ int   s_off[65];
  __shared__ int   s_deg[64];
  float* s_out = s_W;

  build_csr_la(tid, g, ei, ea, s_edge, s_entry, s_off, s_deg, s_la);

  // GEMM: xl/xr = h1 @ Wl2/Wr2 + b  (64x192 @ 192x64, 6 K-chunks of 32)
  const int cg=tid&15, ng=tid>>4, n0=ng*2, gc0=cg*4;
  float accl[2][4], accr[2][4];
  { const float4 blv=*(const float4*)(bl + gc0);
    const float4 brv=*(const float4*)(br + gc0);
    #pragma unroll
    for(int i=0;i<2;i++){
      accl[i][0]=blv.x; accl[i][1]=blv.y; accl[i][2]=blv.z; accl[i][3]=blv.w;
      accr[i][0]=brv.x; accr[i][1]=brv.y; accr[i][2]=brv.z; accr[i][3]=brv.w; } }
  for(int kc=0;kc<6;kc++){
    { int n=tid>>3, kq=tid&7;
      *(float4*)(s_hx + n*36 + kq*4) = *(const float4*)(h1 + (size_t)(base+n)*192 + kc*32 + kq*4); }
    { int k=tid>>4, cc=(tid&15)*4;
      *(float4*)(s_W + k*64 + cc)        = *(const float4*)(Wl + (size_t)(kc*32+k)*64 + cc);
      *(float4*)(s_W + 2048 + k*64 + cc) = *(const float4*)(Wr + (size_t)(kc*32+k)*64 + cc); }
    __syncthreads();
    #pragma unroll
    for(int kq=0;kq<8;kq++){
      float xs0[4], xs1[4];
      { float4 v=*(const float4*)(s_hx + n0*36 + kq*4);     xs0[0]=v.x;xs0[1]=v.y;xs0[2]=v.z;xs0[3]=v.w; }
      { float4 v=*(const float4*)(s_hx + (n0+1)*36 + kq*4); xs1[0]=v.x;xs1[1]=v.y;xs1[2]=v.z;xs1[3]=v.w; }
      #pragma unroll
      for(int f=0;f<4;f++){
        const float4 wl=*(const float4*)(s_W + (kq*4+f)*64 + gc0);
        const float4 wr=*(const float4*)(s_W + 2048 + (kq*4+f)*64 + gc0);
        accl[0][0]+=xs0[f]*wl.x; accl[0][1]+=xs0[f]*wl.y; accl[0][2]+=xs0[f]*wl.z; accl[0][3]+=xs0[f]*wl.w;
        accl[1][0]+=xs1[f]*wl.x; accl[1][1]+=xs1[f]*wl.y; accl[1][2]+=xs1[f]*wl.z; accl[1][3]+=xs1[f]*wl.w;
        accr[0][0]+=xs0[f]*wr.x; accr[0][1]+=xs0[f]*wr.y; accr[0][2]+=xs0[f]*wr.z; accr[0][3]+=xs0[f]*wr.w;
        accr[1][0]+=xs1[f]*wr.x; accr[1][1]+=xs1[f]*wr.y; accr[1][2]+=xs1[f]*wr.z; accr[1][3]+=xs1[f]*wr.w;
      }
    }
    __syncthreads();
  }
  // write xl/xr (swizzled) and stage We2/att2
  #pragma unroll
  for(int i=0;i<2;i++){
    const int n=n0+i, sq=((cg^(n&15))<<2);
    float4 vl; vl.x=accl[i][0]; vl.y=accl[i][1]; vl.z=accl[i][2]; vl.w=accl[i][3];
    float4 vr; vr.x=accr[i][0]; vr.y=accr[i][1]; vr.z=accr[i][2]; vr.w=accr[i][3];
    *(float4*)(s_xl + n*64 + sq)=vl;
    *(float4*)(s_xr + n*64 + sq)=vr;
  }
  if(tid<256){ int f=tid>>4, cc=(tid&15)*4;
    *(float4*)(s_We + f*64 + cc) = *(const float4*)(We + (size_t)f*64 + cc); }
  if(tid<16) *(float4*)(s_att + tid*4) = *(const float4*)(att + tid*4);
  __syncthreads();

  scores_softmax(tid, g, ea, s_entry, s_off, s_la, s_We, s_att, s_xl, s_xr, s_sc);

  // aggregate + bias + ELU into s_out (aliases s_W; GEMM done)
  { const int n=tid>>3, c0a=(tid&7)*8;
    float acc[8]={0.f,0.f,0.f,0.f,0.f,0.f,0.f,0.f};
    const int b=s_off[n], e=s_off[n+1];
    for(int p=b;p<e;p++){
      const int en=s_entry[p], src=en&63;
      const float a=s_sc[p];
      #pragma unroll
      for(int qq=0;qq<2;qq++){
        const int cq=(c0a>>2)+qq;
        const float4 xv=*(const float4*)(s_xl + src*64 + ((cq^(src&15))<<2));
        acc[qq*4+0]+=a*xv.x; acc[qq*4+1]+=a*xv.y; acc[qq*4+2]+=a*xv.z; acc[qq*4+3]+=a*xv.w;
      }
    }
    { const float a=s_sc[EPG+n];
      #pragma unroll
      for(int qq=0;qq<2;qq++){
        const int cq=(c0a>>2)+qq;
        const float4 xv=*(const float4*)(s_xl + n*64 + ((cq^(n&15))<<2));
        acc[qq*4+0]+=a*xv.x; acc[qq*4+1]+=a*xv.y; acc[qq*4+2]+=a*xv.z; acc[qq*4+3]+=a*xv.w;
      } }
    #pragma unroll
    for(int qq=0;qq<2;qq++){
      const float4 bv=*(const float4*)(bias + c0a + qq*4);
      float4 r; r.x=elu_(acc[qq*4+0]+bv.x); r.y=elu_(acc[qq*4+1]+bv.y);
                r.z=elu_(acc[qq*4+2]+bv.z); r.w=elu_(acc[qq*4+3]+bv.w);
      *(float4*)(s_out + n*64 + c0a + qq*4)=r;
    }
  }
  __syncthreads();
  // mean-pool over the 64 nodes
  if(tid<64){ float s=0.f;
    #pragma unroll 8
    for(int n2=0;n2<64;n2++) s += s_out[n2*64+tid];
    s_pool[tid]=s*(1.f/64.f); }
  __syncthreads();
  // LSTM input projection for this timestep: xproj[g][r] = bih[r]+bhh[r]+Wih[r]·pooled
  if(tid<256){
    float a=bih[tid]+bhh[tid];
    #pragma unroll
    for(int kq=0;kq<16;kq++){
      const float4 w=*(const float4*)(Wih + (size_t)tid*64 + kq*4);
      a += w.x*s_pool[kq*4+0] + w.y*s_pool[kq*4+1] + w.z*s_pool[kq*4+2] + w.w*s_pool[kq*4+3];
    }
    xproj[(size_t)g*256 + tid]=a;
  }
}

// ---- LSTM: 256 threads, thread (l,q)=(tid>>2,tid&3): rows {m*64+l} m=0..3, quarter q.
// Weights as 64 NAMED SCALARS (no private array -> no alloca -> no scratch; rule #20).
// Laundered once post-scalarization so loads can't be sunk into the loop.
#define WDECL(m) \
  float w##m##_0,w##m##_1,w##m##_2,w##m##_3,w##m##_4,w##m##_5,w##m##_6,w##m##_7, \
        w##m##_8,w##m##_9,w##m##_10,w##m##_11,w##m##_12,w##m##_13,w##m##_14,w##m##_15; \
  { const float* wp_ = Whh + (size_t)((m)*64+l)*64 + q*16; \
    const float4 a_=*(const float4*)(wp_),   b_=*(const float4*)(wp_+4); \
    const float4 c_=*(const float4*)(wp_+8), d_=*(const float4*)(wp_+12); \
    w##m##_0=a_.x;  w##m##_1=a_.y;  w##m##_2=a_.z;  w##m##_3=a_.w; \
    w##m##_4=b_.x;  w##m##_5=b_.y;  w##m##_6=b_.z;  w##m##_7=b_.w; \
    w##m##_8=c_.x;  w##m##_9=c_.y;  w##m##_10=c_.z; w##m##_11=c_.w; \
    w##m##_12=d_.x; w##m##_13=d_.y; w##m##_14=d_.z; w##m##_15=d_.w; } \
  asm volatile("" : "+v"(w##m##_0),"+v"(w##m##_1),"+v"(w##m##_2),"+v"(w##m##_3), \
                    "+v"(w##m##_4),"+v"(w##m##_5),"+v"(w##m##_6),"+v"(w##m##_7), \
                    "+v"(w##m##_8),"+v"(w##m##_9),"+v"(w##m##_10),"+v"(w##m##_11), \
                    "+v"(w##m##_12),"+v"(w##m##_13),"+v"(w##m##_14),"+v"(w##m##_15));

#define DOT8A(m) (((w##m##_0*hb0 + w##m##_1*hb1) + (w##m##_2*hb2 + w##m##_3*hb3)) + \
                  ((w##m##_4*hb4 + w##m##_5*hb5) + (w##m##_6*hb6 + w##m##_7*hb7)))
#define DOT8B(m) (((w##m##_8*hb8 + w##m##_9*hb9) + (w##m##_10*hb10 + w##m##_11*hb11)) + \
                  ((w##m##_12*hb12 + w##m##_13*hb13) + (w##m##_14*hb14 + w##m##_15*hb15)))

__global__ __launch_bounds__(256,1) void lstm_k(
    const float* __restrict__ xproj, const float* __restrict__ Whh,
    const float* __restrict__ W1, const float* __restrict__ b1,
    const float* __restrict__ W2, const float* __restrict__ b2,
    float* __restrict__ out)
{
  const int tid=threadIdx.x, l=tid>>2, q=tid&3;
  __shared__ __align__(16) float s_h[2][64];
  __shared__ float s_y[32];

  WDECL(0) WDECL(1) WDECL(2) WDECL(3)

  float c=0.f;
  float xp0=xproj[l], xp1=xproj[64+l], xp2=xproj[128+l], xp3=xproj[192+l];
  if(tid<64){ s_h[0][tid]=0.f; s_h[1][tid]=0.f; }
  __syncthreads();
  int cur=0;
  for(int t=0;t<1024;t++){
    float hb0,hb1,hb2,hb3,hb4,hb5,hb6,hb7,hb8,hb9,hb10,hb11,hb12,hb13,hb14,hb15;
    { const float* hp_ = &s_h[cur][q*16];
      const float4 a_=*(const float4*)(hp_),   b_=*(const float4*)(hp_+4);
      const float4 c_=*(const float4*)(hp_+8), d_=*(const float4*)(hp_+12);
      hb0=a_.x;  hb1=a_.y;  hb2=a_.z;  hb3=a_.w;
      hb4=b_.x;  hb5=b_.y;  hb6=b_.z;  hb7=b_.w;
      hb8=c_.x;  hb9=c_.y;  hb10=c_.z; hb11=c_.w;
      hb12=d_.x; hb13=d_.y; hb14=d_.z; hb15=d_.w; }
    // prefetch next timestep's xproj while this step computes
    float xn0=0.f,xn1=0.f,xn2=0.f,xn3=0.f;
    if(t<1023){
      const float* xpp = xproj + (size_t)(t+1)*256;
      xn0=xpp[l]; xn1=xpp[64+l]; xn2=xpp[128+l]; xn3=xpp[192+l];
    }
    float a0=quad_add(DOT8A(0)+DOT8B(0));
    float a1=quad_add(DOT8A(1)+DOT8B(1));
    float a2=quad_add(DOT8A(2)+DOT8B(2));
    float a3=quad_add(DOT8A(3)+DOT8B(3));
    const float gi=a0+xp0, gf=a1+xp1, gg=a2+xp2, go=a3+xp3;
    c = sig_(gf)*c + sig_(gi)*tanhf_(gg);
    const float hn = sig_(go)*tanhf_(c);
    if(q==0) s_h[cur^1][l]=hn;
    xp0=xn0; xp1=xn1; xp2=xn2; xp3=xn3;
    cur^=1;
    __syncthreads();
  }
  // MLP head: relu(h@W1+b1)@W2+b2  (final h is in s_h[cur])
  if(tid<32){
    float a=b1[tid];
    #pragma unroll 8
    for(int k=0;k<64;k++) a += s_h[cur][k]*W1[k*32+tid];
    s_y[tid]=fmaxf(a,0.f);
  }
  __syncthreads();
  if(tid==0){
    float a=b2[0];
    #pragma unroll
    for(int j=0;j<32;j++) a += s_y[j]*W2[j];
    out[0]=a;
  }
}

extern "C" void kernel_launch(void* const* d_in, const int* in_sizes, int n_in,
                              void* d_out, int out_size, void* d_ws, size_t ws_size,
                              hipStream_t stream) {
  (void)in_sizes; (void)n_in; (void)out_size; (void)ws_size;
  const float* x    = (const float*)d_in[0];
  const int*   ei   = (const int*)d_in[1];
  const float* ea   = (const float*)d_in[2];
  const float* Wl1  = (const float*)d_in[4];
  const float* bl1  = (const float*)d_in[5];
  const float* Wr1  = (const float*)d_in[6];
  const float* br1  = (const float*)d_in[7];
  const float* We1  = (const float*)d_in[8];
  const float* att1 = (const float*)d_in[9];
  const float* bias1= (const float*)d_in[10];
  const float* Wl2  = (const float*)d_in[11];
  const float* bl2  = (const float*)d_in[12];
  const float* Wr2  = (const float*)d_in[13];
  const float* br2  = (const float*)d_in[14];
  const float* We2  = (const float*)d_in[15];
  const float* att2 = (const float*)d_in[16];
  const float* bias2= (const float*)d_in[17];
  const float* Wih  = (const float*)d_in[18];
  const float* Whh  = (const float*)d_in[19];
  const float* bih  = (const float*)d_in[20];
  const float* bhh  = (const float*)d_in[21];
  const float* W1   = (const float*)d_in[22];
  const float* b1   = (const float*)d_in[23];
  const float* W2   = (const float*)d_in[24];
  const float* b2   = (const float*)d_in[25];

  float* h1w = (float*)d_ws;                                  // 65536*192*4 = 50331648 B
  float* xpw = (float*)((char*)d_ws + (size_t)50331648);      // 1024*256*4  = 1048576 B
  float* outp = (float*)d_out;

  gat1_k<<<dim3(SGR), dim3(512), 0, stream>>>(x, ei, ea, Wl1, bl1, Wr1, br1, We1, att1, bias1, h1w);
  gat2_k<<<dim3(SGR), dim3(512), 0, stream>>>(h1w, ei, ea, Wl2, bl2, Wr2, br2, We2, att2, bias2,
                                              Wih, bih, bhh, xpw);
  lstm_k<<<dim3(1), dim3(256), 0, stream>>>(xpw, Whh, W1, b1, W2, b2, outp);
}

// Round 7
// 859.431 us; speedup vs baseline: 1.4041x; 1.0523x over previous
//
#include <hip/hip_runtime.h>

#define ETOT 524288
#define SGR  1024
#define NPG  64
#define EPG  512
#define NFD  32
#define EFD  16
#define HCD  64

__device__ __forceinline__ float elu_(float x){ return x>0.f ? x : (__expf(x)-1.f); }
__device__ __forceinline__ float sig_(float x){ return 1.f/(1.f+__expf(-x)); }
__device__ __forceinline__ float tanhf_(float x){ float e=__expf(2.f*x); return 1.f-2.f/(e+1.f); }
__device__ __forceinline__ float lrelu_(float x){ return x>0.f ? x : 0.2f*x; }

template<int C>
__device__ __forceinline__ float dppf(float v){
  return __int_as_float(__builtin_amdgcn_update_dpp(0, __float_as_int(v), C, 0xF, 0xF, true));
}

// sum over the 4 lanes of a quad, result in all 4 lanes — VALU DPP, no LDS pipe
__device__ __forceinline__ float quad_add(float v){
  v += dppf<0xB1>(v);       // [1,0,3,2]
  return v + dppf<0x4E>(v); // [2,3,0,1]
}

// Deterministic CSR build + per-dst mean edge_attr (self-loop fill).
// Called by all 512 threads; contains barriers.
__device__ void build_csr_la(int tid, int g, const int* ei, const float* ea,
                             int* s_edge, int* s_entry, int* s_off, int* s_deg,
                             float* s_la)
{
  const int base = g*NPG;
  const int* srcp = ei + (size_t)g*EPG;
  const int* dstp = ei + (size_t)ETOT + (size_t)g*EPG;
  for(int e=tid;e<EPG;e+=512)
    s_edge[e] = (srcp[e]-base) | ((dstp[e]-base)<<6);
  __syncthreads();
  if(tid<64){ int d=0;
    #pragma unroll 8
    for(int e=0;e<EPG;e++) d += (((s_edge[e]>>6)&63)==tid);
    s_deg[tid]=d; }
  __syncthreads();
  if(tid==0){ int a=0;
    for(int i=0;i<64;i++){ s_off[i]=a; a+=s_deg[i]; }
    s_off[64]=a; }
  __syncthreads();
  if(tid<64){ int pos=s_off[tid];
    for(int e=0;e<EPG;e++){ int en=s_edge[e];
      if(((en>>6)&63)==tid) s_entry[pos++] = (en&63) | (tid<<6) | (e<<12); } }
  __syncthreads();
  if(tid<256){ int n=tid>>2, f0=(tid&3)*4;
    float a0=0,a1=0,a2=0,a3=0;
    const int b=s_off[n], en=s_off[n+1];
    for(int p=b;p<en;p++){ int eid=s_entry[p]>>12;
      const float4 v = *(const float4*)(ea + ((size_t)g*EPG+(size_t)eid)*EFD + f0);
      a0+=v.x; a1+=v.y; a2+=v.z; a3+=v.w; }
    float inv = 1.f/fmaxf((float)(en-b),1.f);
    float4 r; r.x=a0*inv; r.y=a1*inv; r.z=a2*inv; r.w=a3*inv;
    *(float4*)(s_la + n*EFD + f0) = r; }
  __syncthreads();
}

// scores (576 = 512 edges + 64 self loops) + per-dst softmax; alpha left in s_sc.
__device__ void scores_softmax(int tid, int g, const float* ea,
   const int* s_entry, const int* s_off, const float* s_la,
   const float* s_We, const float* s_att, const float* s_xl, const float* s_xr,
   float* s_sc)
{
  for(int p=tid;p<576;p+=512){
    int src,dst; float eav[16];
    if(p<EPG){
      int en=s_entry[p]; src=en&63; dst=(en>>6)&63; int eid=en>>12;
      const float* epp = ea + ((size_t)g*EPG + (size_t)eid)*EFD;
      float4 v0=*(const float4*)(epp),   v1=*(const float4*)(epp+4);
      float4 v2=*(const float4*)(epp+8), v3=*(const float4*)(epp+12);
      eav[0]=v0.x;eav[1]=v0.y;eav[2]=v0.z;eav[3]=v0.w;
      eav[4]=v1.x;eav[5]=v1.y;eav[6]=v1.z;eav[7]=v1.w;
      eav[8]=v2.x;eav[9]=v2.y;eav[10]=v2.z;eav[11]=v2.w;
      eav[12]=v3.x;eav[13]=v3.y;eav[14]=v3.z;eav[15]=v3.w;
    } else {
      int n=p-EPG; src=n; dst=n;
      const float* epp = s_la + n*EFD;
      float4 v0=*(const float4*)(epp),   v1=*(const float4*)(epp+4);
      float4 v2=*(const float4*)(epp+8), v3=*(const float4*)(epp+12);
      eav[0]=v0.x;eav[1]=v0.y;eav[2]=v0.z;eav[3]=v0.w;
      eav[4]=v1.x;eav[5]=v1.y;eav[6]=v1.z;eav[7]=v1.w;
      eav[8]=v2.x;eav[9]=v2.y;eav[10]=v2.z;eav[11]=v2.w;
      eav[12]=v3.x;eav[13]=v3.y;eav[14]=v3.z;eav[15]=v3.w;
    }
    float score=0.f;
    #pragma unroll 4
    for(int cq=0;cq<16;cq++){
      float e0=0.f,e1=0.f,e2=0.f,e3=0.f;
      #pragma unroll
      for(int f=0;f<16;f++){
        const float4 wv=*(const float4*)(s_We + f*64 + cq*4);
        e0+=eav[f]*wv.x; e1+=eav[f]*wv.y; e2+=eav[f]*wv.z; e3+=eav[f]*wv.w;
      }
      const float4 xlv=*(const float4*)(s_xl + src*64 + ((cq^(src&15))<<2));
      const float4 xrv=*(const float4*)(s_xr + dst*64 + ((cq^(dst&15))<<2));
      const float4 av =*(const float4*)(s_att + cq*4);
      float m0=lrelu_(xlv.x+xrv.x+e0), m1=lrelu_(xlv.y+xrv.y+e1);
      float m2=lrelu_(xlv.z+xrv.z+e2), m3=lrelu_(xlv.w+xrv.w+e3);
      score += m0*av.x+m1*av.y+m2*av.z+m3*av.w;
    }
    s_sc[p]=score;
  }
  __syncthreads();
  if(tid<64){
    const int b=s_off[tid], e=s_off[tid+1];
    float mx=s_sc[EPG+tid];
    for(int p=b;p<e;p++) mx=fmaxf(mx,s_sc[p]);
    float v=__expf(s_sc[EPG+tid]-mx); float den=v; s_sc[EPG+tid]=v;
    for(int p=b;p<e;p++){ float w=__expf(s_sc[p]-mx); s_sc[p]=w; den+=w; }
    const float inv=1.f/(den+1e-16f);
    s_sc[EPG+tid]*=inv;
    for(int p=b;p<e;p++) s_sc[p]*=inv;
  }
  __syncthreads();
}

__global__ __launch_bounds__(512,4) void gat1_k(
    const float* __restrict__ x, const int* __restrict__ ei,
    const float* __restrict__ ea, const float* __restrict__ Wl,
    const float* __restrict__ bl, const float* __restrict__ Wr,
    const float* __restrict__ br, const float* __restrict__ We,
    const float* __restrict__ att, const float* __restrict__ bias,
    float* __restrict__ h1)
{
  const int g = blockIdx.x, tid = threadIdx.x;
  const int base = g*NPG;

  __shared__ __align__(16) float s_x[NPG*36];
  __shared__ __align__(16) float s_xl[NPG*64];
  __shared__ __align__(16) float s_xr[NPG*64];
  __shared__ __align__(16) float s_W[2*32*64];
  __shared__ __align__(16) float s_We[16*64];
  __shared__ __align__(16) float s_att[64];
  __shared__ __align__(16) float s_la[NPG*EFD];
  __shared__ float s_sc[576];
  __shared__ int   s_edge[EPG];
  __shared__ int   s_entry[EPG];
  __shared__ int   s_off[65];
  __shared__ int   s_deg[64];

  // stage x tile [64][32] (padded stride 36)
  { int n=tid>>3, kq=tid&7;
    float4 v = *(const float4*)(x + (size_t)(base+n)*NFD + kq*4);
    *(float4*)(s_x + n*36 + kq*4) = v; }

  build_csr_la(tid, g, ei, ea, s_edge, s_entry, s_off, s_deg, s_la);

  for(int h=0;h<3;h++){
    // stage weight slices for this head
    { int k=tid>>4, c0=(tid&15)*4;
      *(float4*)(s_W + k*64 + c0)        = *(const float4*)(Wl + (size_t)k*192 + h*64 + c0);
      *(float4*)(s_W + 2048 + k*64 + c0) = *(const float4*)(Wr + (size_t)k*192 + h*64 + c0); }
    if(tid<256){ int f=tid>>4, c0=(tid&15)*4;
      *(float4*)(s_We + f*64 + c0) = *(const float4*)(We + (size_t)f*192 + h*64 + c0); }
    if(tid<16) *(float4*)(s_att + tid*4) = *(const float4*)(att + h*64 + tid*4);
    __syncthreads();

    // GEMM: xl = x@Wl_h + bl_h ; xr = x@Wr_h + br_h  (64x32 @ 32x64)
    { const int cg=tid&15, ng=tid>>4, n0=ng*2, c0=cg*4;
      const float4 blv=*(const float4*)(bl + h*64 + c0);
      const float4 brv=*(const float4*)(br + h*64 + c0);
      float accl[2][4]={{blv.x,blv.y,blv.z,blv.w},{blv.x,blv.y,blv.z,blv.w}};
      float accr[2][4]={{brv.x,brv.y,brv.z,brv.w},{brv.x,brv.y,brv.z,brv.w}};
      #pragma unroll
      for(int kq=0;kq<8;kq++){
        float xs0[4], xs1[4];
        { float4 v=*(const float4*)(s_x + n0*36 + kq*4);     xs0[0]=v.x;xs0[1]=v.y;xs0[2]=v.z;xs0[3]=v.w; }
        { float4 v=*(const float4*)(s_x + (n0+1)*36 + kq*4); xs1[0]=v.x;xs1[1]=v.y;xs1[2]=v.z;xs1[3]=v.w; }
        #pragma unroll
        for(int f=0;f<4;f++){
          const float4 wl=*(const float4*)(s_W + (kq*4+f)*64 + c0);
          const float4 wr=*(const float4*)(s_W + 2048 + (kq*4+f)*64 + c0);
          accl[0][0]+=xs0[f]*wl.x; accl[0][1]+=xs0[f]*wl.y; accl[0][2]+=xs0[f]*wl.z; accl[0][3]+=xs0[f]*wl.w;
          accl[1][0]+=xs1[f]*wl.x; accl[1][1]+=xs1[f]*wl.y; accl[1][2]+=xs1[f]*wl.z; accl[1][3]+=xs1[f]*wl.w;
          accr[0][0]+=xs0[f]*wr.x; accr[0][1]+=xs0[f]*wr.y; accr[0][2]+=xs0[f]*wr.z; accr[0][3]+=xs0[f]*wr.w;
          accr[1][0]+=xs1[f]*wr.x; accr[1][1]+=xs1[f]*wr.y; accr[1][2]+=xs1[f]*wr.z; accr[1][3]+=xs1[f]*wr.w;
        }
      }
      #pragma unroll
      for(int i=0;i<2;i++){
        const int n=n0+i, sq=((cg^(n&15))<<2);
        float4 vl; vl.x=accl[i][0]; vl.y=accl[i][1]; vl.z=accl[i][2]; vl.w=accl[i][3];
        float4 vr; vr.x=accr[i][0]; vr.y=accr[i][1]; vr.z=accr[i][2]; vr.w=accr[i][3];
        *(float4*)(s_xl + n*64 + sq)=vl;
        *(float4*)(s_xr + n*64 + sq)=vr;
      }
    }
    __syncthreads();

    scores_softmax(tid, g, ea, s_entry, s_off, s_la, s_We, s_att, s_xl, s_xr, s_sc);

    // aggregate alpha * xl[src] per (dst, 8-channel slice) + bias + ELU -> h1
    { const int n=tid>>3, c0a=(tid&7)*8;
      float acc[8]={0.f,0.f,0.f,0.f,0.f,0.f,0.f,0.f};
      const int b=s_off[n], e=s_off[n+1];
      for(int p=b;p<e;p++){
        const int en=s_entry[p], src=en&63;
        const float a=s_sc[p];
        #pragma unroll
        for(int qq=0;qq<2;qq++){
          const int cq=(c0a>>2)+qq;
          const float4 xv=*(const float4*)(s_xl + src*64 + ((cq^(src&15))<<2));
          acc[qq*4+0]+=a*xv.x; acc[qq*4+1]+=a*xv.y; acc[qq*4+2]+=a*xv.z; acc[qq*4+3]+=a*xv.w;
        }
      }
      { const float a=s_sc[EPG+n];
        #pragma unroll
        for(int qq=0;qq<2;qq++){
          const int cq=(c0a>>2)+qq;
          const float4 xv=*(const float4*)(s_xl + n*64 + ((cq^(n&15))<<2));
          acc[qq*4+0]+=a*xv.x; acc[qq*4+1]+=a*xv.y; acc[qq*4+2]+=a*xv.z; acc[qq*4+3]+=a*xv.w;
        } }
      float* op = h1 + (size_t)(base+n)*192 + h*64 + c0a;
      #pragma unroll
      for(int qq=0;qq<2;qq++){
        const float4 bv=*(const float4*)(bias + h*64 + c0a + qq*4);
        float4 r; r.x=elu_(acc[qq*4+0]+bv.x); r.y=elu_(acc[qq*4+1]+bv.y);
                  r.z=elu_(acc[qq*4+2]+bv.z); r.w=elu_(acc[qq*4+3]+bv.w);
        *(float4*)(op + qq*4)=r;
      }
    }
    __syncthreads();
  }
}

__global__ __launch_bounds__(512,4) void gat2_k(
    const float* __restrict__ h1, const int* __restrict__ ei,
    const float* __restrict__ ea, const float* __restrict__ Wl,
    const float* __restrict__ bl, const float* __restrict__ Wr,
    const float* __restrict__ br, const float* __restrict__ We,
    const float* __restrict__ att, const float* __restrict__ bias,
    const float* __restrict__ Wih, const float* __restrict__ bih,
    const float* __restrict__ bhh, float* __restrict__ xproj)
{
  const int g = blockIdx.x, tid = threadIdx.x;
  const int base = g*NPG;

  __shared__ __align__(16) float s_hx[NPG*36];
  __shared__ __align__(16) float s_xl[NPG*64];
  __shared__ __align__(16) float s_xr[NPG*64];
  __shared__ __align__(16) float s_W[2*32*64];   // also reused as s_out (64x64)
  __shared__ __align__(16) float s_We[16*64];
  __shared__ __align__(16) float s_att[64];
  __shared__ __align__(16) float s_la[NPG*EFD];
  __shared__ float s_sc[576];
  __shared__ float s_pool[64];
  __shared__ int   s_edge[EPG];
  __shared__ int   s_entry[EPG];
  __shared__ int   s_off[65];
  __shared__ int   s_deg[64];
  float* s_out = s_W;

  build_csr_la(tid, g, ei, ea, s_edge, s_entry, s_off, s_deg, s_la);

  // GEMM: xl/xr = h1 @ Wl2/Wr2 + b  (64x192 @ 192x64, 6 K-chunks of 32)
  const int cg=tid&15, ng=tid>>4, n0=ng*2, gc0=cg*4;
  float accl[2][4], accr[2][4];
  { const float4 blv=*(const float4*)(bl + gc0);
    const float4 brv=*(const float4*)(br + gc0);
    #pragma unroll
    for(int i=0;i<2;i++){
      accl[i][0]=blv.x; accl[i][1]=blv.y; accl[i][2]=blv.z; accl[i][3]=blv.w;
      accr[i][0]=brv.x; accr[i][1]=brv.y; accr[i][2]=brv.z; accr[i][3]=brv.w; } }
  for(int kc=0;kc<6;kc++){
    { int n=tid>>3, kq=tid&7;
      *(float4*)(s_hx + n*36 + kq*4) = *(const float4*)(h1 + (size_t)(base+n)*192 + kc*32 + kq*4); }
    { int k=tid>>4, cc=(tid&15)*4;
      *(float4*)(s_W + k*64 + cc)        = *(const float4*)(Wl + (size_t)(kc*32+k)*64 + cc);
      *(float4*)(s_W + 2048 + k*64 + cc) = *(const float4*)(Wr + (size_t)(kc*32+k)*64 + cc); }
    __syncthreads();
    #pragma unroll
    for(int kq=0;kq<8;kq++){
      float xs0[4], xs1[4];
      { float4 v=*(const float4*)(s_hx + n0*36 + kq*4);     xs0[0]=v.x;xs0[1]=v.y;xs0[2]=v.z;xs0[3]=v.w; }
      { float4 v=*(const float4*)(s_hx + (n0+1)*36 + kq*4); xs1[0]=v.x;xs1[1]=v.y;xs1[2]=v.z;xs1[3]=v.w; }
      #pragma unroll
      for(int f=0;f<4;f++){
        const float4 wl=*(const float4*)(s_W + (kq*4+f)*64 + gc0);
        const float4 wr=*(const float4*)(s_W + 2048 + (kq*4+f)*64 + gc0);
        accl[0][0]+=xs0[f]*wl.x; accl[0][1]+=xs0[f]*wl.y; accl[0][2]+=xs0[f]*wl.z; accl[0][3]+=xs0[f]*wl.w;
        accl[1][0]+=xs1[f]*wl.x; accl[1][1]+=xs1[f]*wl.y; accl[1][2]+=xs1[f]*wl.z; accl[1][3]+=xs1[f]*wl.w;
        accr[0][0]+=xs0[f]*wr.x; accr[0][1]+=xs0[f]*wr.y; accr[0][2]+=xs0[f]*wr.z; accr[0][3]+=xs0[f]*wr.w;
        accr[1][0]+=xs1[f]*wr.x; accr[1][1]+=xs1[f]*wr.y; accr[1][2]+=xs1[f]*wr.z; accr[1][3]+=xs1[f]*wr.w;
      }
    }
    __syncthreads();
  }
  // write xl/xr (swizzled) and stage We2/att2
  #pragma unroll
  for(int i=0;i<2;i++){
    const int n=n0+i, sq=((cg^(n&15))<<2);
    float4 vl; vl.x=accl[i][0]; vl.y=accl[i][1]; vl.z=accl[i][2]; vl.w=accl[i][3];
    float4 vr; vr.x=accr[i][0]; vr.y=accr[i][1]; vr.z=accr[i][2]; vr.w=accr[i][3];
    *(float4*)(s_xl + n*64 + sq)=vl;
    *(float4*)(s_xr + n*64 + sq)=vr;
  }
  if(tid<256){ int f=tid>>4, cc=(tid&15)*4;
    *(float4*)(s_We + f*64 + cc) = *(const float4*)(We + (size_t)f*64 + cc); }
  if(tid<16) *(float4*)(s_att + tid*4) = *(const float4*)(att + tid*4);
  __syncthreads();

  scores_softmax(tid, g, ea, s_entry, s_off, s_la, s_We, s_att, s_xl, s_xr, s_sc);

  // aggregate + bias + ELU into s_out (aliases s_W; GEMM done)
  { const int n=tid>>3, c0a=(tid&7)*8;
    float acc[8]={0.f,0.f,0.f,0.f,0.f,0.f,0.f,0.f};
    const int b=s_off[n], e=s_off[n+1];
    for(int p=b;p<e;p++){
      const int en=s_entry[p], src=en&63;
      const float a=s_sc[p];
      #pragma unroll
      for(int qq=0;qq<2;qq++){
        const int cq=(c0a>>2)+qq;
        const float4 xv=*(const float4*)(s_xl + src*64 + ((cq^(src&15))<<2));
        acc[qq*4+0]+=a*xv.x; acc[qq*4+1]+=a*xv.y; acc[qq*4+2]+=a*xv.z; acc[qq*4+3]+=a*xv.w;
      }
    }
    { const float a=s_sc[EPG+n];
      #pragma unroll
      for(int qq=0;qq<2;qq++){
        const int cq=(c0a>>2)+qq;
        const float4 xv=*(const float4*)(s_xl + n*64 + ((cq^(n&15))<<2));
        acc[qq*4+0]+=a*xv.x; acc[qq*4+1]+=a*xv.y; acc[qq*4+2]+=a*xv.z; acc[qq*4+3]+=a*xv.w;
      } }
    #pragma unroll
    for(int qq=0;qq<2;qq++){
      const float4 bv=*(const float4*)(bias + c0a + qq*4);
      float4 r; r.x=elu_(acc[qq*4+0]+bv.x); r.y=elu_(acc[qq*4+1]+bv.y);
                r.z=elu_(acc[qq*4+2]+bv.z); r.w=elu_(acc[qq*4+3]+bv.w);
      *(float4*)(s_out + n*64 + c0a + qq*4)=r;
    }
  }
  __syncthreads();
  // mean-pool over the 64 nodes
  if(tid<64){ float s=0.f;
    #pragma unroll 8
    for(int n2=0;n2<64;n2++) s += s_out[n2*64+tid];
    s_pool[tid]=s*(1.f/64.f); }
  __syncthreads();
  // LSTM input projection for this timestep: xproj[g][r] = bih[r]+bhh[r]+Wih[r]·pooled
  if(tid<256){
    float a=bih[tid]+bhh[tid];
    #pragma unroll
    for(int kq=0;kq<16;kq++){
      const float4 w=*(const float4*)(Wih + (size_t)tid*64 + kq*4);
      a += w.x*s_pool[kq*4+0] + w.y*s_pool[kq*4+1] + w.z*s_pool[kq*4+2] + w.w*s_pool[kq*4+3];
    }
    xproj[(size_t)g*256 + tid]=a;
  }
}

// ---- LSTM: 256 threads, thread (l,q)=(tid>>2,tid&3): rows {m*64+l} m=0..3, quarter q.
// Weights as 64 NAMED SCALARS; amdgpu_waves_per_eu(1,1) pins the RA budget to the
// full 512-VGPR/wave tier (r6 post-mortem: __launch_bounds__(256,1) left the budget
// at the 8-wave/64-VGPR tier -> 64 scratch reloads/step).
#define WDECL(m) \
  float w##m##_0,w##m##_1,w##m##_2,w##m##_3,w##m##_4,w##m##_5,w##m##_6,w##m##_7, \
        w##m##_8,w##m##_9,w##m##_10,w##m##_11,w##m##_12,w##m##_13,w##m##_14,w##m##_15; \
  { const float* wp_ = Whh + (size_t)((m)*64+l)*64 + q*16; \
    const float4 a_=*(const float4*)(wp_),   b_=*(const float4*)(wp_+4); \
    const float4 c_=*(const float4*)(wp_+8), d_=*(const float4*)(wp_+12); \
    w##m##_0=a_.x;  w##m##_1=a_.y;  w##m##_2=a_.z;  w##m##_3=a_.w; \
    w##m##_4=b_.x;  w##m##_5=b_.y;  w##m##_6=b_.z;  w##m##_7=b_.w; \
    w##m##_8=c_.x;  w##m##_9=c_.y;  w##m##_10=c_.z; w##m##_11=c_.w; \
    w##m##_12=d_.x; w##m##_13=d_.y; w##m##_14=d_.z; w##m##_15=d_.w; } \
  asm volatile("" : "+v"(w##m##_0),"+v"(w##m##_1),"+v"(w##m##_2),"+v"(w##m##_3), \
                    "+v"(w##m##_4),"+v"(w##m##_5),"+v"(w##m##_6),"+v"(w##m##_7), \
                    "+v"(w##m##_8),"+v"(w##m##_9),"+v"(w##m##_10),"+v"(w##m##_11), \
                    "+v"(w##m##_12),"+v"(w##m##_13),"+v"(w##m##_14),"+v"(w##m##_15));

#define DOT8A(m) (((w##m##_0*hb0 + w##m##_1*hb1) + (w##m##_2*hb2 + w##m##_3*hb3)) + \
                  ((w##m##_4*hb4 + w##m##_5*hb5) + (w##m##_6*hb6 + w##m##_7*hb7)))
#define DOT8B(m) (((w##m##_8*hb8 + w##m##_9*hb9) + (w##m##_10*hb10 + w##m##_11*hb11)) + \
                  ((w##m##_12*hb12 + w##m##_13*hb13) + (w##m##_14*hb14 + w##m##_15*hb15)))

__global__ __attribute__((amdgpu_flat_work_group_size(256,256), amdgpu_waves_per_eu(1,1)))
void lstm_k(
    const float* __restrict__ xproj, const float* __restrict__ Whh,
    const float* __restrict__ W1, const float* __restrict__ b1,
    const float* __restrict__ W2, const float* __restrict__ b2,
    float* __restrict__ out)
{
  const int tid=threadIdx.x, l=tid>>2, q=tid&3;
  __shared__ __align__(16) float s_h[2][64];
  __shared__ float s_y[32];

  WDECL(0) WDECL(1) WDECL(2) WDECL(3)

  float c=0.f;
  float xp0=xproj[l], xp1=xproj[64+l], xp2=xproj[128+l], xp3=xproj[192+l];
  if(tid<64){ s_h[0][tid]=0.f; s_h[1][tid]=0.f; }
  __syncthreads();
  int cur=0;
  for(int t=0;t<1024;t++){
    float hb0,hb1,hb2,hb3,hb4,hb5,hb6,hb7,hb8,hb9,hb10,hb11,hb12,hb13,hb14,hb15;
    { const float* hp_ = &s_h[cur][q*16];
      const float4 a_=*(const float4*)(hp_),   b_=*(const float4*)(hp_+4);
      const float4 c_=*(const float4*)(hp_+8), d_=*(const float4*)(hp_+12);
      hb0=a_.x;  hb1=a_.y;  hb2=a_.z;  hb3=a_.w;
      hb4=b_.x;  hb5=b_.y;  hb6=b_.z;  hb7=b_.w;
      hb8=c_.x;  hb9=c_.y;  hb10=c_.z; hb11=c_.w;
      hb12=d_.x; hb13=d_.y; hb14=d_.z; hb15=d_.w; }
    // prefetch next timestep's xproj while this step computes
    float xn0=0.f,xn1=0.f,xn2=0.f,xn3=0.f;
    if(t<1023){
      const float* xpp = xproj + (size_t)(t+1)*256;
      xn0=xpp[l]; xn1=xpp[64+l]; xn2=xpp[128+l]; xn3=xpp[192+l];
    }
    float a0=quad_add(DOT8A(0)+DOT8B(0));
    float a1=quad_add(DOT8A(1)+DOT8B(1));
    float a2=quad_add(DOT8A(2)+DOT8B(2));
    float a3=quad_add(DOT8A(3)+DOT8B(3));
    const float gi=a0+xp0, gf=a1+xp1, gg=a2+xp2, go=a3+xp3;
    c = sig_(gf)*c + sig_(gi)*tanhf_(gg);
    const float hn = sig_(go)*tanhf_(c);
    if(q==0) s_h[cur^1][l]=hn;
    xp0=xn0; xp1=xn1; xp2=xn2; xp3=xn3;
    cur^=1;
    __syncthreads();
  }
  // MLP head: relu(h@W1+b1)@W2+b2  (final h is in s_h[cur])
  if(tid<32){
    float a=b1[tid];
    #pragma unroll 8
    for(int k=0;k<64;k++) a += s_h[cur][k]*W1[k*32+tid];
    s_y[tid]=fmaxf(a,0.f);
  }
  __syncthreads();
  if(tid==0){
    float a=b2[0];
    #pragma unroll
    for(int j=0;j<32;j++) a += s_y[j]*W2[j];
    out[0]=a;
  }
}

extern "C" void kernel_launch(void* const* d_in, const int* in_sizes, int n_in,
                              void* d_out, int out_size, void* d_ws, size_t ws_size,
                              hipStream_t stream) {
  (void)in_sizes; (void)n_in; (void)out_size; (void)ws_size;
  const float* x    = (const float*)d_in[0];
  const int*   ei   = (const int*)d_in[1];
  const float* ea   = (const float*)d_in[2];
  const float* Wl1  = (const float*)d_in[4];
  const float* bl1  = (const float*)d_in[5];
  const float* Wr1  = (const float*)d_in[6];
  const float* br1  = (const float*)d_in[7];
  const float* We1  = (const float*)d_in[8];
  const float* att1 = (const float*)d_in[9];
  const float* bias1= (const float*)d_in[10];
  const float* Wl2  = (const float*)d_in[11];
  const float* bl2  = (const float*)d_in[12];
  const float* Wr2  = (const float*)d_in[13];
  const float* br2  = (const float*)d_in[14];
  const float* We2  = (const float*)d_in[15];
  const float* att2 = (const float*)d_in[16];
  const float* bias2= (const float*)d_in[17];
  const float* Wih  = (const float*)d_in[18];
  const float* Whh  = (const float*)d_in[19];
  const float* bih  = (const float*)d_in[20];
  const float* bhh  = (const float*)d_in[21];
  const float* W1   = (const float*)d_in[22];
  const float* b1   = (const float*)d_in[23];
  const float* W2   = (const float*)d_in[24];
  const float* b2   = (const float*)d_in[25];

  float* h1w = (float*)d_ws;                                  // 65536*192*4 = 50331648 B
  float* xpw = (float*)((char*)d_ws + (size_t)50331648);      // 1024*256*4  = 1048576 B
  float* outp = (float*)d_out;

  gat1_k<<<dim3(SGR), dim3(512), 0, stream>>>(x, ei, ea, Wl1, bl1, Wr1, br1, We1, att1, bias1, h1w);
  gat2_k<<<dim3(SGR), dim3(512), 0, stream>>>(h1w, ei, ea, Wl2, bl2, Wr2, br2, We2, att2, bias2,
                                              Wih, bih, bhh, xpw);
  lstm_k<<<dim3(1), dim3(256), 0, stream>>>(xpw, Whh, W1, b1, W2, b2, outp);
}

// Round 8
// 676.692 us; speedup vs baseline: 1.7833x; 1.2700x over previous
//
#include <hip/hip_runtime.h>

#define ETOT 524288
#define SGR  1024
#define NPG  64
#define EPG  512
#define NFD  32
#define EFD  16
#define HCD  64

typedef float f2v __attribute__((ext_vector_type(2)));

__device__ __forceinline__ float elu_(float x){ return x>0.f ? x : (__expf(x)-1.f); }
__device__ __forceinline__ float sig_(float x){ return 1.f/(1.f+__expf(-x)); }
__device__ __forceinline__ float tanhf_(float x){ float e=__expf(2.f*x); return 1.f-2.f/(e+1.f); }
__device__ __forceinline__ float lrelu_(float x){ return x>0.f ? x : 0.2f*x; }

template<int C>
__device__ __forceinline__ float dppf(float v){
  return __int_as_float(__builtin_amdgcn_update_dpp(0, __float_as_int(v), C, 0xF, 0xF, true));
}

// sum over the 4 lanes of a quad, result in all 4 lanes — VALU DPP, no LDS pipe
__device__ __forceinline__ float quad_add(float v){
  v += dppf<0xB1>(v);       // [1,0,3,2]
  return v + dppf<0x4E>(v); // [2,3,0,1]
}

// Deterministic CSR build + per-dst mean edge_attr (self-loop fill).
// r8: fully parallel (sliced 64x8 counting + sliced scatter) — removes the two
// single-wave 512-iteration convoys. Bin entry order identical to the serial scan.
__device__ void build_csr_la(int tid, int g, const int* ei, const float* ea,
                             int* s_edge, int* s_entry, int* s_off, int* s_deg,
                             int* s_cnt, float* s_la)
{
  const int base = g*NPG;
  const int* srcp = ei + (size_t)g*EPG;
  const int* dstp = ei + (size_t)ETOT + (size_t)g*EPG;
  s_edge[tid] = (srcp[tid]-base) | ((dstp[tid]-base)<<6);   // 512 threads, 1 edge each
  __syncthreads();
  // sliced counts: thread (d,s) counts dst==d within edge slice [s*64,(s+1)*64)
  { const int d=tid>>3, s=tid&7, b0=s*64;
    int c=0;
    #pragma unroll 8
    for(int i=0;i<64;i++) c += (((s_edge[b0+i]>>6)&63)==d);
    s_cnt[(d<<3)|s]=c; }
  __syncthreads();
  if(tid<64){ int a=0;
    #pragma unroll
    for(int s=0;s<8;s++) a+=s_cnt[(tid<<3)|s];
    s_deg[tid]=a; }
  __syncthreads();
  if(tid==0){ int a=0;
    for(int i=0;i<64;i++){ s_off[i]=a; a+=s_deg[i]; }
    s_off[64]=a; }
  __syncthreads();
  // sliced scatter: thread (d,s) places its slice's matches at s_off[d] + sum of
  // earlier slices' counts — global edge order preserved within each bin.
  { const int d=tid>>3, s=tid&7, b0=s*64;
    int pos=s_off[d];
    for(int s2=0;s2<s;s2++) pos += s_cnt[(d<<3)|s2];
    for(int i=0;i<64;i++){ int en=s_edge[b0+i];
      if(((en>>6)&63)==d) s_entry[pos++] = (en&63) | (d<<6) | ((b0+i)<<12); } }
  __syncthreads();
  if(tid<256){ int n=tid>>2, f0=(tid&3)*4;
    float a0=0,a1=0,a2=0,a3=0;
    const int b=s_off[n], en=s_off[n+1];
    for(int p=b;p<en;p++){ int eid=s_entry[p]>>12;
      const float4 v = *(const float4*)(ea + ((size_t)g*EPG+(size_t)eid)*EFD + f0);
      a0+=v.x; a1+=v.y; a2+=v.z; a3+=v.w; }
    float inv = 1.f/fmaxf((float)(en-b),1.f);
    float4 r; r.x=a0*inv; r.y=a1*inv; r.z=a2*inv; r.w=a3*inv;
    *(float4*)(s_la + n*EFD + f0) = r; }
  __syncthreads();
}

// scores (576 = 512 edges + 64 self loops) + per-dst softmax; alpha left in s_sc.
// r8: softmax parallelized — 8 lanes per dst, DPP 8-lane reduce (xor1/xor2/halfmirror).
__device__ void scores_softmax(int tid, int g, const float* ea,
   const int* s_entry, const int* s_off, const float* s_la,
   const float* s_We, const float* s_att, const float* s_xl, const float* s_xr,
   float* s_sc)
{
  for(int p=tid;p<576;p+=512){
    int src,dst; float eav[16];
    if(p<EPG){
      int en=s_entry[p]; src=en&63; dst=(en>>6)&63; int eid=en>>12;
      const float* epp = ea + ((size_t)g*EPG + (size_t)eid)*EFD;
      float4 v0=*(const float4*)(epp),   v1=*(const float4*)(epp+4);
      float4 v2=*(const float4*)(epp+8), v3=*(const float4*)(epp+12);
      eav[0]=v0.x;eav[1]=v0.y;eav[2]=v0.z;eav[3]=v0.w;
      eav[4]=v1.x;eav[5]=v1.y;eav[6]=v1.z;eav[7]=v1.w;
      eav[8]=v2.x;eav[9]=v2.y;eav[10]=v2.z;eav[11]=v2.w;
      eav[12]=v3.x;eav[13]=v3.y;eav[14]=v3.z;eav[15]=v3.w;
    } else {
      int n=p-EPG; src=n; dst=n;
      const float* epp = s_la + n*EFD;
      float4 v0=*(const float4*)(epp),   v1=*(const float4*)(epp+4);
      float4 v2=*(const float4*)(epp+8), v3=*(const float4*)(epp+12);
      eav[0]=v0.x;eav[1]=v0.y;eav[2]=v0.z;eav[3]=v0.w;
      eav[4]=v1.x;eav[5]=v1.y;eav[6]=v1.z;eav[7]=v1.w;
      eav[8]=v2.x;eav[9]=v2.y;eav[10]=v2.z;eav[11]=v2.w;
      eav[12]=v3.x;eav[13]=v3.y;eav[14]=v3.z;eav[15]=v3.w;
    }
    float score=0.f;
    #pragma unroll 4
    for(int cq=0;cq<16;cq++){
      float e0=0.f,e1=0.f,e2=0.f,e3=0.f;
      #pragma unroll
      for(int f=0;f<16;f++){
        const float4 wv=*(const float4*)(s_We + f*64 + cq*4);
        e0+=eav[f]*wv.x; e1+=eav[f]*wv.y; e2+=eav[f]*wv.z; e3+=eav[f]*wv.w;
      }
      const float4 xlv=*(const float4*)(s_xl + src*64 + ((cq^(src&15))<<2));
      const float4 xrv=*(const float4*)(s_xr + dst*64 + ((cq^(dst&15))<<2));
      const float4 av =*(const float4*)(s_att + cq*4);
      float m0=lrelu_(xlv.x+xrv.x+e0), m1=lrelu_(xlv.y+xrv.y+e1);
      float m2=lrelu_(xlv.z+xrv.z+e2), m3=lrelu_(xlv.w+xrv.w+e3);
      score += m0*av.x+m1*av.y+m2*av.z+m3*av.w;
    }
    s_sc[p]=score;
  }
  __syncthreads();
  // parallel per-dst softmax: 8 contiguous lanes per dst; DPP 8-lane reduce.
  { const int d=tid>>3, s=tid&7;
    const int b=s_off[d], e=s_off[d+1];
    float mx=-1e30f;
    for(int p=b+s;p<e;p+=8) mx=fmaxf(mx,s_sc[p]);
    if(s==0) mx=fmaxf(mx,s_sc[EPG+d]);
    mx=fmaxf(mx,dppf<0xB1>(mx));
    mx=fmaxf(mx,dppf<0x4E>(mx));
    mx=fmaxf(mx,dppf<0x141>(mx));   // row_half_mirror: completes 8-lane reduce
    float den=0.f;
    for(int p=b+s;p<e;p+=8){ float w=__expf(s_sc[p]-mx); s_sc[p]=w; den+=w; }
    float selfv=0.f;
    if(s==0){ selfv=__expf(s_sc[EPG+d]-mx); den+=selfv; }
    den+=dppf<0xB1>(den);
    den+=dppf<0x4E>(den);
    den+=dppf<0x141>(den);
    const float inv=1.f/(den+1e-16f);
    for(int p=b+s;p<e;p+=8) s_sc[p]*=inv;
    if(s==0) s_sc[EPG+d]=selfv*inv;
  }
  __syncthreads();
}

__global__ __launch_bounds__(512,4) void gat1_k(
    const float* __restrict__ x, const int* __restrict__ ei,
    const float* __restrict__ ea, const float* __restrict__ Wl,
    const float* __restrict__ bl, const float* __restrict__ Wr,
    const float* __restrict__ br, const float* __restrict__ We,
    const float* __restrict__ att, const float* __restrict__ bias,
    float* __restrict__ h1)
{
  const int g = blockIdx.x, tid = threadIdx.x;
  const int base = g*NPG;

  __shared__ __align__(16) float s_x[NPG*36];
  __shared__ __align__(16) float s_xl[NPG*64];
  __shared__ __align__(16) float s_xr[NPG*64];
  __shared__ __align__(16) float s_W[2*32*64];
  __shared__ __align__(16) float s_We[16*64];
  __shared__ __align__(16) float s_att[64];
  __shared__ __align__(16) float s_la[NPG*EFD];
  __shared__ float s_sc[576];
  __shared__ int   s_edge[EPG];
  __shared__ int   s_entry[EPG];
  __shared__ int   s_cnt[512];
  __shared__ int   s_off[65];
  __shared__ int   s_deg[64];

  // stage x tile [64][32] (padded stride 36)
  { int n=tid>>3, kq=tid&7;
    float4 v = *(const float4*)(x + (size_t)(base+n)*NFD + kq*4);
    *(float4*)(s_x + n*36 + kq*4) = v; }

  build_csr_la(tid, g, ei, ea, s_edge, s_entry, s_off, s_deg, s_cnt, s_la);

  for(int h=0;h<3;h++){
    // stage weight slices for this head
    { int k=tid>>4, c0=(tid&15)*4;
      *(float4*)(s_W + k*64 + c0)        = *(const float4*)(Wl + (size_t)k*192 + h*64 + c0);
      *(float4*)(s_W + 2048 + k*64 + c0) = *(const float4*)(Wr + (size_t)k*192 + h*64 + c0); }
    if(tid<256){ int f=tid>>4, c0=(tid&15)*4;
      *(float4*)(s_We + f*64 + c0) = *(const float4*)(We + (size_t)f*192 + h*64 + c0); }
    if(tid<16) *(float4*)(s_att + tid*4) = *(const float4*)(att + h*64 + tid*4);
    __syncthreads();

    // GEMM: xl = x@Wl_h + bl_h ; xr = x@Wr_h + br_h  (64x32 @ 32x64)
    { const int cg=tid&15, ng=tid>>4, n0=ng*2, c0=cg*4;
      const float4 blv=*(const float4*)(bl + h*64 + c0);
      const float4 brv=*(const float4*)(br + h*64 + c0);
      float accl[2][4]={{blv.x,blv.y,blv.z,blv.w},{blv.x,blv.y,blv.z,blv.w}};
      float accr[2][4]={{brv.x,brv.y,brv.z,brv.w},{brv.x,brv.y,brv.z,brv.w}};
      #pragma unroll
      for(int kq=0;kq<8;kq++){
        float xs0[4], xs1[4];
        { float4 v=*(const float4*)(s_x + n0*36 + kq*4);     xs0[0]=v.x;xs0[1]=v.y;xs0[2]=v.z;xs0[3]=v.w; }
        { float4 v=*(const float4*)(s_x + (n0+1)*36 + kq*4); xs1[0]=v.x;xs1[1]=v.y;xs1[2]=v.z;xs1[3]=v.w; }
        #pragma unroll
        for(int f=0;f<4;f++){
          const float4 wl=*(const float4*)(s_W + (kq*4+f)*64 + c0);
          const float4 wr=*(const float4*)(s_W + 2048 + (kq*4+f)*64 + c0);
          accl[0][0]+=xs0[f]*wl.x; accl[0][1]+=xs0[f]*wl.y; accl[0][2]+=xs0[f]*wl.z; accl[0][3]+=xs0[f]*wl.w;
          accl[1][0]+=xs1[f]*wl.x; accl[1][1]+=xs1[f]*wl.y; accl[1][2]+=xs1[f]*wl.z; accl[1][3]+=xs1[f]*wl.w;
          accr[0][0]+=xs0[f]*wr.x; accr[0][1]+=xs0[f]*wr.y; accr[0][2]+=xs0[f]*wr.z; accr[0][3]+=xs0[f]*wr.w;
          accr[1][0]+=xs1[f]*wr.x; accr[1][1]+=xs1[f]*wr.y; accr[1][2]+=xs1[f]*wr.z; accr[1][3]+=xs1[f]*wr.w;
        }
      }
      #pragma unroll
      for(int i=0;i<2;i++){
        const int n=n0+i, sq=((cg^(n&15))<<2);
        float4 vl; vl.x=accl[i][0]; vl.y=accl[i][1]; vl.z=accl[i][2]; vl.w=accl[i][3];
        float4 vr; vr.x=accr[i][0]; vr.y=accr[i][1]; vr.z=accr[i][2]; vr.w=accr[i][3];
        *(float4*)(s_xl + n*64 + sq)=vl;
        *(float4*)(s_xr + n*64 + sq)=vr;
      }
    }
    __syncthreads();

    scores_softmax(tid, g, ea, s_entry, s_off, s_la, s_We, s_att, s_xl, s_xr, s_sc);

    // aggregate alpha * xl[src] per (dst, 8-channel slice) + bias + ELU -> h1
    { const int n=tid>>3, c0a=(tid&7)*8;
      float acc[8]={0.f,0.f,0.f,0.f,0.f,0.f,0.f,0.f};
      const int b=s_off[n], e=s_off[n+1];
      for(int p=b;p<e;p++){
        const int en=s_entry[p], src=en&63;
        const float a=s_sc[p];
        #pragma unroll
        for(int qq=0;qq<2;qq++){
          const int cq=(c0a>>2)+qq;
          const float4 xv=*(const float4*)(s_xl + src*64 + ((cq^(src&15))<<2));
          acc[qq*4+0]+=a*xv.x; acc[qq*4+1]+=a*xv.y; acc[qq*4+2]+=a*xv.z; acc[qq*4+3]+=a*xv.w;
        }
      }
      { const float a=s_sc[EPG+n];
        #pragma unroll
        for(int qq=0;qq<2;qq++){
          const int cq=(c0a>>2)+qq;
          const float4 xv=*(const float4*)(s_xl + n*64 + ((cq^(n&15))<<2));
          acc[qq*4+0]+=a*xv.x; acc[qq*4+1]+=a*xv.y; acc[qq*4+2]+=a*xv.z; acc[qq*4+3]+=a*xv.w;
        } }
      float* op = h1 + (size_t)(base+n)*192 + h*64 + c0a;
      #pragma unroll
      for(int qq=0;qq<2;qq++){
        const float4 bv=*(const float4*)(bias + h*64 + c0a + qq*4);
        float4 r; r.x=elu_(acc[qq*4+0]+bv.x); r.y=elu_(acc[qq*4+1]+bv.y);
                  r.z=elu_(acc[qq*4+2]+bv.z); r.w=elu_(acc[qq*4+3]+bv.w);
        *(float4*)(op + qq*4)=r;
      }
    }
    __syncthreads();
  }
}

__global__ __launch_bounds__(512,4) void gat2_k(
    const float* __restrict__ h1, const int* __restrict__ ei,
    const float* __restrict__ ea, const float* __restrict__ Wl,
    const float* __restrict__ bl, const float* __restrict__ Wr,
    const float* __restrict__ br, const float* __restrict__ We,
    const float* __restrict__ att, const float* __restrict__ bias,
    const float* __restrict__ Wih, const float* __restrict__ bih,
    const float* __restrict__ bhh, float* __restrict__ xproj)
{
  const int g = blockIdx.x, tid = threadIdx.x;
  const int base = g*NPG;

  __shared__ __align__(16) float s_hx[NPG*36];
  __shared__ __align__(16) float s_xl[NPG*64];
  __shared__ __align__(16) float s_xr[NPG*64];
  __shared__ __align__(16) float s_W[2*32*64];   // also reused as s_out (64x64)
  __shared__ __align__(16) float s_We[16*64];
  __shared__ __align__(16) float s_att[64];
  __shared__ __align__(16) float s_la[NPG*EFD];
  __shared__ float s_sc[576];
  __shared__ float s_pool[64];
  __shared__ int   s_edge[EPG];
  __shared__ int   s_entry[EPG];
  __shared__ int   s_cnt[512];
  __shared__ int   s_off[65];
  __shared__ int   s_deg[64];
  float* s_out = s_W;

  build_csr_la(tid, g, ei, ea, s_edge, s_entry, s_off, s_deg, s_cnt, s_la);

  // GEMM: xl/xr = h1 @ Wl2/Wr2 + b  (64x192 @ 192x64, 6 K-chunks of 32)
  const int cg=tid&15, ng=tid>>4, n0=ng*2, gc0=cg*4;
  float accl[2][4], accr[2][4];
  { const float4 blv=*(const float4*)(bl + gc0);
    const float4 brv=*(const float4*)(br + gc0);
    #pragma unroll
    for(int i=0;i<2;i++){
      accl[i][0]=blv.x; accl[i][1]=blv.y; accl[i][2]=blv.z; accl[i][3]=blv.w;
      accr[i][0]=brv.x; accr[i][1]=brv.y; accr[i][2]=brv.z; accr[i][3]=brv.w; } }
  for(int kc=0;kc<6;kc++){
    { int n=tid>>3, kq=tid&7;
      *(float4*)(s_hx + n*36 + kq*4) = *(const float4*)(h1 + (size_t)(base+n)*192 + kc*32 + kq*4); }
    { int k=tid>>4, cc=(tid&15)*4;
      *(float4*)(s_W + k*64 + cc)        = *(const float4*)(Wl + (size_t)(kc*32+k)*64 + cc);
      *(float4*)(s_W + 2048 + k*64 + cc) = *(const float4*)(Wr + (size_t)(kc*32+k)*64 + cc); }
    __syncthreads();
    #pragma unroll
    for(int kq=0;kq<8;kq++){
      float xs0[4], xs1[4];
      { float4 v=*(const float4*)(s_hx + n0*36 + kq*4);     xs0[0]=v.x;xs0[1]=v.y;xs0[2]=v.z;xs0[3]=v.w; }
      { float4 v=*(const float4*)(s_hx + (n0+1)*36 + kq*4); xs1[0]=v.x;xs1[1]=v.y;xs1[2]=v.z;xs1[3]=v.w; }
      #pragma unroll
      for(int f=0;f<4;f++){
        const float4 wl=*(const float4*)(s_W + (kq*4+f)*64 + gc0);
        const float4 wr=*(const float4*)(s_W + 2048 + (kq*4+f)*64 + gc0);
        accl[0][0]+=xs0[f]*wl.x; accl[0][1]+=xs0[f]*wl.y; accl[0][2]+=xs0[f]*wl.z; accl[0][3]+=xs0[f]*wl.w;
        accl[1][0]+=xs1[f]*wl.x; accl[1][1]+=xs1[f]*wl.y; accl[1][2]+=xs1[f]*wl.z; accl[1][3]+=xs1[f]*wl.w;
        accr[0][0]+=xs0[f]*wr.x; accr[0][1]+=xs0[f]*wr.y; accr[0][2]+=xs0[f]*wr.z; accr[0][3]+=xs0[f]*wr.w;
        accr[1][0]+=xs1[f]*wr.x; accr[1][1]+=xs1[f]*wr.y; accr[1][2]+=xs1[f]*wr.z; accr[1][3]+=xs1[f]*wr.w;
      }
    }
    __syncthreads();
  }
  // write xl/xr (swizzled) and stage We2/att2
  #pragma unroll
  for(int i=0;i<2;i++){
    const int n=n0+i, sq=((cg^(n&15))<<2);
    float4 vl; vl.x=accl[i][0]; vl.y=accl[i][1]; vl.z=accl[i][2]; vl.w=accl[i][3];
    float4 vr; vr.x=accr[i][0]; vr.y=accr[i][1]; vr.z=accr[i][2]; vr.w=accr[i][3];
    *(float4*)(s_xl + n*64 + sq)=vl;
    *(float4*)(s_xr + n*64 + sq)=vr;
  }
  if(tid<256){ int f=tid>>4, cc=(tid&15)*4;
    *(float4*)(s_We + f*64 + cc) = *(const float4*)(We + (size_t)f*64 + cc); }
  if(tid<16) *(float4*)(s_att + tid*4) = *(const float4*)(att + tid*4);
  __syncthreads();

  scores_softmax(tid, g, ea, s_entry, s_off, s_la, s_We, s_att, s_xl, s_xr, s_sc);

  // aggregate + bias + ELU into s_out (aliases s_W; GEMM done)
  { const int n=tid>>3, c0a=(tid&7)*8;
    float acc[8]={0.f,0.f,0.f,0.f,0.f,0.f,0.f,0.f};
    const int b=s_off[n], e=s_off[n+1];
    for(int p=b;p<e;p++){
      const int en=s_entry[p], src=en&63;
      const float a=s_sc[p];
      #pragma unroll
      for(int qq=0;qq<2;qq++){
        const int cq=(c0a>>2)+qq;
        const float4 xv=*(const float4*)(s_xl + src*64 + ((cq^(src&15))<<2));
        acc[qq*4+0]+=a*xv.x; acc[qq*4+1]+=a*xv.y; acc[qq*4+2]+=a*xv.z; acc[qq*4+3]+=a*xv.w;
      }
    }
    { const float a=s_sc[EPG+n];
      #pragma unroll
      for(int qq=0;qq<2;qq++){
        const int cq=(c0a>>2)+qq;
        const float4 xv=*(const float4*)(s_xl + n*64 + ((cq^(n&15))<<2));
        acc[qq*4+0]+=a*xv.x; acc[qq*4+1]+=a*xv.y; acc[qq*4+2]+=a*xv.z; acc[qq*4+3]+=a*xv.w;
      } }
    #pragma unroll
    for(int qq=0;qq<2;qq++){
      const float4 bv=*(const float4*)(bias + c0a + qq*4);
      float4 r; r.x=elu_(acc[qq*4+0]+bv.x); r.y=elu_(acc[qq*4+1]+bv.y);
                r.z=elu_(acc[qq*4+2]+bv.z); r.w=elu_(acc[qq*4+3]+bv.w);
      *(float4*)(s_out + n*64 + c0a + qq*4)=r;
    }
  }
  __syncthreads();
  // mean-pool over the 64 nodes
  if(tid<64){ float s=0.f;
    #pragma unroll 8
    for(int n2=0;n2<64;n2++) s += s_out[n2*64+tid];
    s_pool[tid]=s*(1.f/64.f); }
  __syncthreads();
  // LSTM input projection for this timestep: xproj[g][r] = bih[r]+bhh[r]+Wih[r]·pooled
  if(tid<256){
    float a=bih[tid]+bhh[tid];
    #pragma unroll
    for(int kq=0;kq<16;kq++){
      const float4 w=*(const float4*)(Wih + (size_t)tid*64 + kq*4);
      a += w.x*s_pool[kq*4+0] + w.y*s_pool[kq*4+1] + w.z*s_pool[kq*4+2] + w.w*s_pool[kq*4+3];
    }
    xproj[(size_t)g*256 + tid]=a;
  }
}

// ---- LSTM: 256 threads, thread (l,q)=(tid>>2,tid&3): rows {m*64+l} m=0..3, quarter q.
// Weights as NAMED float2 vectors -> v_pk_fma_f32 (2 MACs/inst, halves FMA issue).
// amdgpu_waves_per_eu(1,1) pins the full 512-VGPR budget (r7: verified VGPR=132, resident).
__device__ __forceinline__ float dot2_(f2v w0,f2v w1,f2v w2,f2v w3,f2v w4,f2v w5,f2v w6,f2v w7,
                                       f2v h0,f2v h1,f2v h2,f2v h3,f2v h4,f2v h5,f2v h6,f2v h7){
  f2v a = w0*h0; a += w1*h1; a += w2*h2; a += w3*h3;
  f2v b = w4*h4; b += w5*h5; b += w6*h6; b += w7*h7;
  f2v s = a+b; return s[0]+s[1];
}

#define WDECL(m) \
  f2v w##m##_0,w##m##_1,w##m##_2,w##m##_3,w##m##_4,w##m##_5,w##m##_6,w##m##_7; \
  { const float* wp_ = Whh + (size_t)((m)*64+l)*64 + q*16; \
    const float4 a_=*(const float4*)(wp_),   b_=*(const float4*)(wp_+4); \
    const float4 c_=*(const float4*)(wp_+8), d_=*(const float4*)(wp_+12); \
    w##m##_0=(f2v){a_.x,a_.y}; w##m##_1=(f2v){a_.z,a_.w}; \
    w##m##_2=(f2v){b_.x,b_.y}; w##m##_3=(f2v){b_.z,b_.w}; \
    w##m##_4=(f2v){c_.x,c_.y}; w##m##_5=(f2v){c_.z,c_.w}; \
    w##m##_6=(f2v){d_.x,d_.y}; w##m##_7=(f2v){d_.z,d_.w}; } \
  asm volatile("" : "+v"(w##m##_0),"+v"(w##m##_1),"+v"(w##m##_2),"+v"(w##m##_3), \
                    "+v"(w##m##_4),"+v"(w##m##_5),"+v"(w##m##_6),"+v"(w##m##_7));

#define DOTP(m) dot2_(w##m##_0,w##m##_1,w##m##_2,w##m##_3,w##m##_4,w##m##_5,w##m##_6,w##m##_7, \
                      hb0,hb1,hb2,hb3,hb4,hb5,hb6,hb7)

__global__ __attribute__((amdgpu_flat_work_group_size(256,256), amdgpu_waves_per_eu(1,1)))
void lstm_k(
    const float* __restrict__ xproj, const float* __restrict__ Whh,
    const float* __restrict__ W1, const float* __restrict__ b1,
    const float* __restrict__ W2, const float* __restrict__ b2,
    float* __restrict__ out)
{
  const int tid=threadIdx.x, l=tid>>2, q=tid&3;
  __shared__ __align__(16) float s_h[2][64];
  __shared__ float s_y[32];

  WDECL(0) WDECL(1) WDECL(2) WDECL(3)

  float c=0.f;
  float xp0=xproj[l], xp1=xproj[64+l], xp2=xproj[128+l], xp3=xproj[192+l];
  if(tid<64){ s_h[0][tid]=0.f; s_h[1][tid]=0.f; }
  __syncthreads();
  int cur=0;
  for(int t=0;t<1024;t++){
    f2v hb0,hb1,hb2,hb3,hb4,hb5,hb6,hb7;
    { const float* hp_ = &s_h[cur][q*16];
      const float4 a_=*(const float4*)(hp_),   b_=*(const float4*)(hp_+4);
      const float4 c_=*(const float4*)(hp_+8), d_=*(const float4*)(hp_+12);
      hb0=(f2v){a_.x,a_.y}; hb1=(f2v){a_.z,a_.w};
      hb2=(f2v){b_.x,b_.y}; hb3=(f2v){b_.z,b_.w};
      hb4=(f2v){c_.x,c_.y}; hb5=(f2v){c_.z,c_.w};
      hb6=(f2v){d_.x,d_.y}; hb7=(f2v){d_.z,d_.w}; }
    // prefetch next timestep's xproj while this step computes
    float xn0=0.f,xn1=0.f,xn2=0.f,xn3=0.f;
    if(t<1023){
      const float* xpp = xproj + (size_t)(t+1)*256;
      xn0=xpp[l]; xn1=xpp[64+l]; xn2=xpp[128+l]; xn3=xpp[192+l];
    }
    float a0=quad_add(DOTP(0));
    float a1=quad_add(DOTP(1));
    float a2=quad_add(DOTP(2));
    float a3=quad_add(DOTP(3));
    const float gi=a0+xp0, gf=a1+xp1, gg=a2+xp2, go=a3+xp3;
    c = sig_(gf)*c + sig_(gi)*tanhf_(gg);
    const float hn = sig_(go)*tanhf_(c);
    if(q==0) s_h[cur^1][l]=hn;
    xp0=xn0; xp1=xn1; xp2=xn2; xp3=xn3;
    cur^=1;
    __syncthreads();
  }
  // MLP head: relu(h@W1+b1)@W2+b2  (final h is in s_h[cur])
  if(tid<32){
    float a=b1[tid];
    #pragma unroll 8
    for(int k=0;k<64;k++) a += s_h[cur][k]*W1[k*32+tid];
    s_y[tid]=fmaxf(a,0.f);
  }
  __syncthreads();
  if(tid==0){
    float a=b2[0];
    #pragma unroll
    for(int j=0;j<32;j++) a += s_y[j]*W2[j];
    out[0]=a;
  }
}

extern "C" void kernel_launch(void* const* d_in, const int* in_sizes, int n_in,
                              void* d_out, int out_size, void* d_ws, size_t ws_size,
                              hipStream_t stream) {
  (void)in_sizes; (void)n_in; (void)out_size; (void)ws_size;
  const float* x    = (const float*)d_in[0];
  const int*   ei   = (const int*)d_in[1];
  const float* ea   = (const float*)d_in[2];
  const float* Wl1  = (const float*)d_in[4];
  const float* bl1  = (const float*)d_in[5];
  const float* Wr1  = (const float*)d_in[6];
  const float* br1  = (const float*)d_in[7];
  const float* We1  = (const float*)d_in[8];
  const float* att1 = (const float*)d_in[9];
  const float* bias1= (const float*)d_in[10];
  const float* Wl2  = (const float*)d_in[11];
  const float* bl2  = (const float*)d_in[12];
  const float* Wr2  = (const float*)d_in[13];
  const float* br2  = (const float*)d_in[14];
  const float* We2  = (const float*)d_in[15];
  const float* att2 = (const float*)d_in[16];
  const float* bias2= (const float*)d_in[17];
  const float* Wih  = (const float*)d_in[18];
  const float* Whh  = (const float*)d_in[19];
  const float* bih  = (const float*)d_in[20];
  const float* bhh  = (const float*)d_in[21];
  const float* W1   = (const float*)d_in[22];
  const float* b1   = (const float*)d_in[23];
  const float* W2   = (const float*)d_in[24];
  const float* b2   = (const float*)d_in[25];

  float* h1w = (float*)d_ws;                                  // 65536*192*4 = 50331648 B
  float* xpw = (float*)((char*)d_ws + (size_t)50331648);      // 1024*256*4  = 1048576 B
  float* outp = (float*)d_out;

  gat1_k<<<dim3(SGR), dim3(512), 0, stream>>>(x, ei, ea, Wl1, bl1, Wr1, br1, We1, att1, bias1, h1w);
  gat2_k<<<dim3(SGR), dim3(512), 0, stream>>>(h1w, ei, ea, Wl2, bl2, Wr2, br2, We2, att2, bias2,
                                              Wih, bih, bhh, xpw);
  lstm_k<<<dim3(1), dim3(256), 0, stream>>>(xpw, Whh, W1, b1, W2, b2, outp);
}

// Round 9
// 668.329 us; speedup vs baseline: 1.8056x; 1.0125x over previous
//
#include <hip/hip_runtime.h>

#define ETOT 524288
#define SGR  1024
#define NPG  64
#define EPG  512
#define NFD  32
#define EFD  16
#define HCD  64

typedef float f2v __attribute__((ext_vector_type(2)));

__device__ __forceinline__ float elu_(float x){ return x>0.f ? x : (__expf(x)-1.f); }
__device__ __forceinline__ float sig_(float x){ return 1.f/(1.f+__expf(-x)); }
__device__ __forceinline__ float tanhf_(float x){ float e=__expf(2.f*x); return 1.f-2.f/(e+1.f); }
__device__ __forceinline__ float lrelu_(float x){ return x>0.f ? x : 0.2f*x; }

template<int C>
__device__ __forceinline__ float dppf(float v){
  return __int_as_float(__builtin_amdgcn_update_dpp(0, __float_as_int(v), C, 0xF, 0xF, true));
}

// sum over the 4 lanes of a quad, result in all 4 lanes — VALU DPP, no LDS pipe
__device__ __forceinline__ float quad_add(float v){
  v += dppf<0xB1>(v);       // [1,0,3,2]
  return v + dppf<0x4E>(v); // [2,3,0,1]
}

// Deterministic CSR build + per-dst mean edge_attr (self-loop fill).
// Fully parallel (sliced 64x8 counting + sliced scatter); bin order = serial scan order.
__device__ void build_csr_la(int tid, int g, const int* ei, const float* ea,
                             int* s_edge, int* s_entry, int* s_off, int* s_deg,
                             int* s_cnt, float* s_la)
{
  const int base = g*NPG;
  const int* srcp = ei + (size_t)g*EPG;
  const int* dstp = ei + (size_t)ETOT + (size_t)g*EPG;
  s_edge[tid] = (srcp[tid]-base) | ((dstp[tid]-base)<<6);   // 512 threads, 1 edge each
  __syncthreads();
  { const int d=tid>>3, s=tid&7, b0=s*64;
    int c=0;
    #pragma unroll 8
    for(int i=0;i<64;i++) c += (((s_edge[b0+i]>>6)&63)==d);
    s_cnt[(d<<3)|s]=c; }
  __syncthreads();
  if(tid<64){ int a=0;
    #pragma unroll
    for(int s=0;s<8;s++) a+=s_cnt[(tid<<3)|s];
    s_deg[tid]=a; }
  __syncthreads();
  if(tid==0){ int a=0;
    for(int i=0;i<64;i++){ s_off[i]=a; a+=s_deg[i]; }
    s_off[64]=a; }
  __syncthreads();
  { const int d=tid>>3, s=tid&7, b0=s*64;
    int pos=s_off[d];
    for(int s2=0;s2<s;s2++) pos += s_cnt[(d<<3)|s2];
    for(int i=0;i<64;i++){ int en=s_edge[b0+i];
      if(((en>>6)&63)==d) s_entry[pos++] = (en&63) | (d<<6) | ((b0+i)<<12); } }
  __syncthreads();
  if(tid<256){ int n=tid>>2, f0=(tid&3)*4;
    float a0=0,a1=0,a2=0,a3=0;
    const int b=s_off[n], en=s_off[n+1];
    for(int p=b;p<en;p++){ int eid=s_entry[p]>>12;
      const float4 v = *(const float4*)(ea + ((size_t)g*EPG+(size_t)eid)*EFD + f0);
      a0+=v.x; a1+=v.y; a2+=v.z; a3+=v.w; }
    float inv = 1.f/fmaxf((float)(en-b),1.f);
    float4 r; r.x=a0*inv; r.y=a1*inv; r.z=a2*inv; r.w=a3*inv;
    *(float4*)(s_la + n*EFD + f0) = r; }
  __syncthreads();
}

// scores (576 = 512 edges + 64 self loops) + per-dst softmax; alpha left in s_sc.
// softmax: 8 lanes per dst, DPP 8-lane reduce (xor1/xor2/halfmirror).
__device__ void scores_softmax(int tid, int g, const float* ea,
   const int* s_entry, const int* s_off, const float* s_la,
   const float* s_We, const float* s_att, const float* s_xl, const float* s_xr,
   float* s_sc)
{
  for(int p=tid;p<576;p+=512){
    int src,dst; float eav[16];
    if(p<EPG){
      int en=s_entry[p]; src=en&63; dst=(en>>6)&63; int eid=en>>12;
      const float* epp = ea + ((size_t)g*EPG + (size_t)eid)*EFD;
      float4 v0=*(const float4*)(epp),   v1=*(const float4*)(epp+4);
      float4 v2=*(const float4*)(epp+8), v3=*(const float4*)(epp+12);
      eav[0]=v0.x;eav[1]=v0.y;eav[2]=v0.z;eav[3]=v0.w;
      eav[4]=v1.x;eav[5]=v1.y;eav[6]=v1.z;eav[7]=v1.w;
      eav[8]=v2.x;eav[9]=v2.y;eav[10]=v2.z;eav[11]=v2.w;
      eav[12]=v3.x;eav[13]=v3.y;eav[14]=v3.z;eav[15]=v3.w;
    } else {
      int n=p-EPG; src=n; dst=n;
      const float* epp = s_la + n*EFD;
      float4 v0=*(const float4*)(epp),   v1=*(const float4*)(epp+4);
      float4 v2=*(const float4*)(epp+8), v3=*(const float4*)(epp+12);
      eav[0]=v0.x;eav[1]=v0.y;eav[2]=v0.z;eav[3]=v0.w;
      eav[4]=v1.x;eav[5]=v1.y;eav[6]=v1.z;eav[7]=v1.w;
      eav[8]=v2.x;eav[9]=v2.y;eav[10]=v2.z;eav[11]=v2.w;
      eav[12]=v3.x;eav[13]=v3.y;eav[14]=v3.z;eav[15]=v3.w;
    }
    float score=0.f;
    #pragma unroll 4
    for(int cq=0;cq<16;cq++){
      float e0=0.f,e1=0.f,e2=0.f,e3=0.f;
      #pragma unroll
      for(int f=0;f<16;f++){
        const float4 wv=*(const float4*)(s_We + f*64 + cq*4);
        e0+=eav[f]*wv.x; e1+=eav[f]*wv.y; e2+=eav[f]*wv.z; e3+=eav[f]*wv.w;
      }
      const float4 xlv=*(const float4*)(s_xl + src*64 + ((cq^(src&15))<<2));
      const float4 xrv=*(const float4*)(s_xr + dst*64 + ((cq^(dst&15))<<2));
      const float4 av =*(const float4*)(s_att + cq*4);
      float m0=lrelu_(xlv.x+xrv.x+e0), m1=lrelu_(xlv.y+xrv.y+e1);
      float m2=lrelu_(xlv.z+xrv.z+e2), m3=lrelu_(xlv.w+xrv.w+e3);
      score += m0*av.x+m1*av.y+m2*av.z+m3*av.w;
    }
    s_sc[p]=score;
  }
  __syncthreads();
  { const int d=tid>>3, s=tid&7;
    const int b=s_off[d], e=s_off[d+1];
    float mx=-1e30f;
    for(int p=b+s;p<e;p+=8) mx=fmaxf(mx,s_sc[p]);
    if(s==0) mx=fmaxf(mx,s_sc[EPG+d]);
    mx=fmaxf(mx,dppf<0xB1>(mx));
    mx=fmaxf(mx,dppf<0x4E>(mx));
    mx=fmaxf(mx,dppf<0x141>(mx));   // row_half_mirror: completes 8-lane reduce
    float den=0.f;
    for(int p=b+s;p<e;p+=8){ float w=__expf(s_sc[p]-mx); s_sc[p]=w; den+=w; }
    float selfv=0.f;
    if(s==0){ selfv=__expf(s_sc[EPG+d]-mx); den+=selfv; }
    den+=dppf<0xB1>(den);
    den+=dppf<0x4E>(den);
    den+=dppf<0x141>(den);
    const float inv=1.f/(den+1e-16f);
    for(int p=b+s;p<e;p+=8) s_sc[p]*=inv;
    if(s==0) s_sc[EPG+d]=selfv*inv;
  }
  __syncthreads();
}

__global__ __launch_bounds__(512,4) void gat1_k(
    const float* __restrict__ x, const int* __restrict__ ei,
    const float* __restrict__ ea, const float* __restrict__ Wl,
    const float* __restrict__ bl, const float* __restrict__ Wr,
    const float* __restrict__ br, const float* __restrict__ We,
    const float* __restrict__ att, const float* __restrict__ bias,
    float* __restrict__ h1)
{
  const int g = blockIdx.x, tid = threadIdx.x;
  const int base = g*NPG;

  __shared__ __align__(16) float s_x[NPG*36];
  __shared__ __align__(16) float s_xl[NPG*64];
  __shared__ __align__(16) float s_xr[NPG*64];
  __shared__ __align__(16) float s_W[2*32*64];
  __shared__ __align__(16) float s_We[16*64];
  __shared__ __align__(16) float s_att[64];
  __shared__ __align__(16) float s_la[NPG*EFD];
  __shared__ float s_sc[576];
  __shared__ int   s_edge[EPG];
  __shared__ int   s_entry[EPG];
  __shared__ int   s_cnt[512];
  __shared__ int   s_off[65];
  __shared__ int   s_deg[64];

  // stage x tile [64][32] (padded stride 36)
  { int n=tid>>3, kq=tid&7;
    float4 v = *(const float4*)(x + (size_t)(base+n)*NFD + kq*4);
    *(float4*)(s_x + n*36 + kq*4) = v; }

  build_csr_la(tid, g, ei, ea, s_edge, s_entry, s_off, s_deg, s_cnt, s_la);

  for(int h=0;h<3;h++){
    // stage weight slices for this head
    { int k=tid>>4, c0=(tid&15)*4;
      *(float4*)(s_W + k*64 + c0)        = *(const float4*)(Wl + (size_t)k*192 + h*64 + c0);
      *(float4*)(s_W + 2048 + k*64 + c0) = *(const float4*)(Wr + (size_t)k*192 + h*64 + c0); }
    if(tid<256){ int f=tid>>4, c0=(tid&15)*4;
      *(float4*)(s_We + f*64 + c0) = *(const float4*)(We + (size_t)f*192 + h*64 + c0); }
    if(tid<16) *(float4*)(s_att + tid*4) = *(const float4*)(att + h*64 + tid*4);
    __syncthreads();

    // GEMM: xl = x@Wl_h + bl_h ; xr = x@Wr_h + br_h  (64x32 @ 32x64)
    { const int cg=tid&15, ng=tid>>4, n0=ng*2, c0=cg*4;
      const float4 blv=*(const float4*)(bl + h*64 + c0);
      const float4 brv=*(const float4*)(br + h*64 + c0);
      float accl[2][4]={{blv.x,blv.y,blv.z,blv.w},{blv.x,blv.y,blv.z,blv.w}};
      float accr[2][4]={{brv.x,brv.y,brv.z,brv.w},{brv.x,brv.y,brv.z,brv.w}};
      #pragma unroll
      for(int kq=0;kq<8;kq++){
        float xs0[4], xs1[4];
        { float4 v=*(const float4*)(s_x + n0*36 + kq*4);     xs0[0]=v.x;xs0[1]=v.y;xs0[2]=v.z;xs0[3]=v.w; }
        { float4 v=*(const float4*)(s_x + (n0+1)*36 + kq*4); xs1[0]=v.x;xs1[1]=v.y;xs1[2]=v.z;xs1[3]=v.w; }
        #pragma unroll
        for(int f=0;f<4;f++){
          const float4 wl=*(const float4*)(s_W + (kq*4+f)*64 + c0);
          const float4 wr=*(const float4*)(s_W + 2048 + (kq*4+f)*64 + c0);
          accl[0][0]+=xs0[f]*wl.x; accl[0][1]+=xs0[f]*wl.y; accl[0][2]+=xs0[f]*wl.z; accl[0][3]+=xs0[f]*wl.w;
          accl[1][0]+=xs1[f]*wl.x; accl[1][1]+=xs1[f]*wl.y; accl[1][2]+=xs1[f]*wl.z; accl[1][3]+=xs1[f]*wl.w;
          accr[0][0]+=xs0[f]*wr.x; accr[0][1]+=xs0[f]*wr.y; accr[0][2]+=xs0[f]*wr.z; accr[0][3]+=xs0[f]*wr.w;
          accr[1][0]+=xs1[f]*wr.x; accr[1][1]+=xs1[f]*wr.y; accr[1][2]+=xs1[f]*wr.z; accr[1][3]+=xs1[f]*wr.w;
        }
      }
      #pragma unroll
      for(int i=0;i<2;i++){
        const int n=n0+i, sq=((cg^(n&15))<<2);
        float4 vl; vl.x=accl[i][0]; vl.y=accl[i][1]; vl.z=accl[i][2]; vl.w=accl[i][3];
        float4 vr; vr.x=accr[i][0]; vr.y=accr[i][1]; vr.z=accr[i][2]; vr.w=accr[i][3];
        *(float4*)(s_xl + n*64 + sq)=vl;
        *(float4*)(s_xr + n*64 + sq)=vr;
      }
    }
    __syncthreads();

    scores_softmax(tid, g, ea, s_entry, s_off, s_la, s_We, s_att, s_xl, s_xr, s_sc);

    // aggregate alpha * xl[src] per (dst, 8-channel slice) + bias + ELU -> h1
    { const int n=tid>>3, c0a=(tid&7)*8;
      float acc[8]={0.f,0.f,0.f,0.f,0.f,0.f,0.f,0.f};
      const int b=s_off[n], e=s_off[n+1];
      for(int p=b;p<e;p++){
        const int en=s_entry[p], src=en&63;
        const float a=s_sc[p];
        #pragma unroll
        for(int qq=0;qq<2;qq++){
          const int cq=(c0a>>2)+qq;
          const float4 xv=*(const float4*)(s_xl + src*64 + ((cq^(src&15))<<2));
          acc[qq*4+0]+=a*xv.x; acc[qq*4+1]+=a*xv.y; acc[qq*4+2]+=a*xv.z; acc[qq*4+3]+=a*xv.w;
        }
      }
      { const float a=s_sc[EPG+n];
        #pragma unroll
        for(int qq=0;qq<2;qq++){
          const int cq=(c0a>>2)+qq;
          const float4 xv=*(const float4*)(s_xl + n*64 + ((cq^(n&15))<<2));
          acc[qq*4+0]+=a*xv.x; acc[qq*4+1]+=a*xv.y; acc[qq*4+2]+=a*xv.z; acc[qq*4+3]+=a*xv.w;
        } }
      float* op = h1 + (size_t)(base+n)*192 + h*64 + c0a;
      #pragma unroll
      for(int qq=0;qq<2;qq++){
        const float4 bv=*(const float4*)(bias + h*64 + c0a + qq*4);
        float4 r; r.x=elu_(acc[qq*4+0]+bv.x); r.y=elu_(acc[qq*4+1]+bv.y);
                  r.z=elu_(acc[qq*4+2]+bv.z); r.w=elu_(acc[qq*4+3]+bv.w);
        *(float4*)(op + qq*4)=r;
      }
    }
    __syncthreads();
  }
}

__global__ __launch_bounds__(512,4) void gat2_k(
    const float* __restrict__ h1, const int* __restrict__ ei,
    const float* __restrict__ ea, const float* __restrict__ Wl,
    const float* __restrict__ bl, const float* __restrict__ Wr,
    const float* __restrict__ br, const float* __restrict__ We,
    const float* __restrict__ att, const float* __restrict__ bias,
    const float* __restrict__ Wih, const float* __restrict__ bih,
    const float* __restrict__ bhh, float* __restrict__ xproj)
{
  const int g = blockIdx.x, tid = threadIdx.x;
  const int base = g*NPG;

  __shared__ __align__(16) float s_hx[NPG*36];
  __shared__ __align__(16) float s_xl[NPG*64];
  __shared__ __align__(16) float s_xr[NPG*64];
  __shared__ __align__(16) float s_W[2*32*64];   // also reused as s_out (64x64)
  __shared__ __align__(16) float s_We[16*64];
  __shared__ __align__(16) float s_att[64];
  __shared__ __align__(16) float s_la[NPG*EFD];
  __shared__ float s_sc[576];
  __shared__ float s_pool[64];
  __shared__ int   s_edge[EPG];
  __shared__ int   s_entry[EPG];
  __shared__ int   s_cnt[512];
  __shared__ int   s_off[65];
  __shared__ int   s_deg[64];
  float* s_out = s_W;

  build_csr_la(tid, g, ei, ea, s_edge, s_entry, s_off, s_deg, s_cnt, s_la);

  // GEMM: xl/xr = h1 @ Wl2/Wr2 + b  (64x192 @ 192x64, 6 K-chunks of 32)
  const int cg=tid&15, ng=tid>>4, n0=ng*2, gc0=cg*4;
  float accl[2][4], accr[2][4];
  { const float4 blv=*(const float4*)(bl + gc0);
    const float4 brv=*(const float4*)(br + gc0);
    #pragma unroll
    for(int i=0;i<2;i++){
      accl[i][0]=blv.x; accl[i][1]=blv.y; accl[i][2]=blv.z; accl[i][3]=blv.w;
      accr[i][0]=brv.x; accr[i][1]=brv.y; accr[i][2]=brv.z; accr[i][3]=brv.w; } }
  for(int kc=0;kc<6;kc++){
    { int n=tid>>3, kq=tid&7;
      *(float4*)(s_hx + n*36 + kq*4) = *(const float4*)(h1 + (size_t)(base+n)*192 + kc*32 + kq*4); }
    { int k=tid>>4, cc=(tid&15)*4;
      *(float4*)(s_W + k*64 + cc)        = *(const float4*)(Wl + (size_t)(kc*32+k)*64 + cc);
      *(float4*)(s_W + 2048 + k*64 + cc) = *(const float4*)(Wr + (size_t)(kc*32+k)*64 + cc); }
    __syncthreads();
    #pragma unroll
    for(int kq=0;kq<8;kq++){
      float xs0[4], xs1[4];
      { float4 v=*(const float4*)(s_hx + n0*36 + kq*4);     xs0[0]=v.x;xs0[1]=v.y;xs0[2]=v.z;xs0[3]=v.w; }
      { float4 v=*(const float4*)(s_hx + (n0+1)*36 + kq*4); xs1[0]=v.x;xs1[1]=v.y;xs1[2]=v.z;xs1[3]=v.w; }
      #pragma unroll
      for(int f=0;f<4;f++){
        const float4 wl=*(const float4*)(s_W + (kq*4+f)*64 + gc0);
        const float4 wr=*(const float4*)(s_W + 2048 + (kq*4+f)*64 + gc0);
        accl[0][0]+=xs0[f]*wl.x; accl[0][1]+=xs0[f]*wl.y; accl[0][2]+=xs0[f]*wl.z; accl[0][3]+=xs0[f]*wl.w;
        accl[1][0]+=xs1[f]*wl.x; accl[1][1]+=xs1[f]*wl.y; accl[1][2]+=xs1[f]*wl.z; accl[1][3]+=xs1[f]*wl.w;
        accr[0][0]+=xs0[f]*wr.x; accr[0][1]+=xs0[f]*wr.y; accr[0][2]+=xs0[f]*wr.z; accr[0][3]+=xs0[f]*wr.w;
        accr[1][0]+=xs1[f]*wr.x; accr[1][1]+=xs1[f]*wr.y; accr[1][2]+=xs1[f]*wr.z; accr[1][3]+=xs1[f]*wr.w;
      }
    }
    __syncthreads();
  }
  // write xl/xr (swizzled) and stage We2/att2
  #pragma unroll
  for(int i=0;i<2;i++){
    const int n=n0+i, sq=((cg^(n&15))<<2);
    float4 vl; vl.x=accl[i][0]; vl.y=accl[i][1]; vl.z=accl[i][2]; vl.w=accl[i][3];
    float4 vr; vr.x=accr[i][0]; vr.y=accr[i][1]; vr.z=accr[i][2]; vr.w=accr[i][3];
    *(float4*)(s_xl + n*64 + sq)=vl;
    *(float4*)(s_xr + n*64 + sq)=vr;
  }
  if(tid<256){ int f=tid>>4, cc=(tid&15)*4;
    *(float4*)(s_We + f*64 + cc) = *(const float4*)(We + (size_t)f*64 + cc); }
  if(tid<16) *(float4*)(s_att + tid*4) = *(const float4*)(att + tid*4);
  __syncthreads();

  scores_softmax(tid, g, ea, s_entry, s_off, s_la, s_We, s_att, s_xl, s_xr, s_sc);

  // aggregate + bias + ELU into s_out (aliases s_W; GEMM done)
  { const int n=tid>>3, c0a=(tid&7)*8;
    float acc[8]={0.f,0.f,0.f,0.f,0.f,0.f,0.f,0.f};
    const int b=s_off[n], e=s_off[n+1];
    for(int p=b;p<e;p++){
      const int en=s_entry[p], src=en&63;
      const float a=s_sc[p];
      #pragma unroll
      for(int qq=0;qq<2;qq++){
        const int cq=(c0a>>2)+qq;
        const float4 xv=*(const float4*)(s_xl + src*64 + ((cq^(src&15))<<2));
        acc[qq*4+0]+=a*xv.x; acc[qq*4+1]+=a*xv.y; acc[qq*4+2]+=a*xv.z; acc[qq*4+3]+=a*xv.w;
      }
    }
    { const float a=s_sc[EPG+n];
      #pragma unroll
      for(int qq=0;qq<2;qq++){
        const int cq=(c0a>>2)+qq;
        const float4 xv=*(const float4*)(s_xl + n*64 + ((cq^(n&15))<<2));
        acc[qq*4+0]+=a*xv.x; acc[qq*4+1]+=a*xv.y; acc[qq*4+2]+=a*xv.z; acc[qq*4+3]+=a*xv.w;
      } }
    #pragma unroll
    for(int qq=0;qq<2;qq++){
      const float4 bv=*(const float4*)(bias + c0a + qq*4);
      float4 r; r.x=elu_(acc[qq*4+0]+bv.x); r.y=elu_(acc[qq*4+1]+bv.y);
                r.z=elu_(acc[qq*4+2]+bv.z); r.w=elu_(acc[qq*4+3]+bv.w);
      *(float4*)(s_out + n*64 + c0a + qq*4)=r;
    }
  }
  __syncthreads();
  // mean-pool over the 64 nodes
  if(tid<64){ float s=0.f;
    #pragma unroll 8
    for(int n2=0;n2<64;n2++) s += s_out[n2*64+tid];
    s_pool[tid]=s*(1.f/64.f); }
  __syncthreads();
  // LSTM input projection for this timestep: xproj[g][r] = bih[r]+bhh[r]+Wih[r]·pooled
  if(tid<256){
    float a=bih[tid]+bhh[tid];
    #pragma unroll
    for(int kq=0;kq<16;kq++){
      const float4 w=*(const float4*)(Wih + (size_t)tid*64 + kq*4);
      a += w.x*s_pool[kq*4+0] + w.y*s_pool[kq*4+1] + w.z*s_pool[kq*4+2] + w.w*s_pool[kq*4+3];
    }
    xproj[(size_t)g*256 + tid]=a;
  }
}

// ---- LSTM: 256 threads, thread (l,q)=(tid>>2,tid&3): rows {m*64+l} m=0..3, quarter q.
// Weights as NAMED float2 vectors -> v_pk_fma_f32. waves_per_eu(1,1) pins the 512-VGPR
// budget (r7: VGPR=132 resident). r9: DEPTH-4 xproj prefetch ring (statically indexed
// via 4x loop unroll) — r8 showed ~550 cyc/step of exposed cold-HBM latency from the
// 1-deep prefetch (issue-to-use ~350 cyc < ~900 cyc HBM latency; m126).
__device__ __forceinline__ float dot2_(f2v w0,f2v w1,f2v w2,f2v w3,f2v w4,f2v w5,f2v w6,f2v w7,
                                       f2v h0,f2v h1,f2v h2,f2v h3,f2v h4,f2v h5,f2v h6,f2v h7){
  f2v a = w0*h0; a += w1*h1; a += w2*h2; a += w3*h3;
  f2v b = w4*h4; b += w5*h5; b += w6*h6; b += w7*h7;
  f2v s = a+b; return s[0]+s[1];
}

#define WDECL(m) \
  f2v w##m##_0,w##m##_1,w##m##_2,w##m##_3,w##m##_4,w##m##_5,w##m##_6,w##m##_7; \
  { const float* wp_ = Whh + (size_t)((m)*64+l)*64 + q*16; \
    const float4 a_=*(const float4*)(wp_),   b_=*(const float4*)(wp_+4); \
    const float4 c_=*(const float4*)(wp_+8), d_=*(const float4*)(wp_+12); \
    w##m##_0=(f2v){a_.x,a_.y}; w##m##_1=(f2v){a_.z,a_.w}; \
    w##m##_2=(f2v){b_.x,b_.y}; w##m##_3=(f2v){b_.z,b_.w}; \
    w##m##_4=(f2v){c_.x,c_.y}; w##m##_5=(f2v){c_.z,c_.w}; \
    w##m##_6=(f2v){d_.x,d_.y}; w##m##_7=(f2v){d_.z,d_.w}; } \
  asm volatile("" : "+v"(w##m##_0),"+v"(w##m##_1),"+v"(w##m##_2),"+v"(w##m##_3), \
                    "+v"(w##m##_4),"+v"(w##m##_5),"+v"(w##m##_6),"+v"(w##m##_7));

#define DOTP(m) dot2_(w##m##_0,w##m##_1,w##m##_2,w##m##_3,w##m##_4,w##m##_5,w##m##_6,w##m##_7, \
                      hb0,hb1,hb2,hb3,hb4,hb5,hb6,hb7)

// prefetch ring slot k: 4 floats (gate offsets 0,64,128,192)
#define XQDECL(k) \
  float xq##k##_0,xq##k##_1,xq##k##_2,xq##k##_3; \
  { const float* xpp_ = xproj + (size_t)(k)*256; \
    xq##k##_0=xpp_[l]; xq##k##_1=xpp_[64+l]; xq##k##_2=xpp_[128+l]; xq##k##_3=xpp_[192+l]; }

// one LSTM step using (and refilling) ring slot k; t = tb+k
#define STEP(k) { \
    f2v hb0,hb1,hb2,hb3,hb4,hb5,hb6,hb7; \
    { const float* hp_ = &s_h[cur][q*16]; \
      const float4 a_=*(const float4*)(hp_),   b_=*(const float4*)(hp_+4); \
      const float4 c_=*(const float4*)(hp_+8), d_=*(const float4*)(hp_+12); \
      hb0=(f2v){a_.x,a_.y}; hb1=(f2v){a_.z,a_.w}; \
      hb2=(f2v){b_.x,b_.y}; hb3=(f2v){b_.z,b_.w}; \
      hb4=(f2v){c_.x,c_.y}; hb5=(f2v){c_.z,c_.w}; \
      hb6=(f2v){d_.x,d_.y}; hb7=(f2v){d_.z,d_.w}; } \
    const float cx0=xq##k##_0, cx1=xq##k##_1, cx2=xq##k##_2, cx3=xq##k##_3; \
    if(tb+(k)+4<1024){ \
      const float* xpp_ = xproj + (size_t)(tb+(k)+4)*256; \
      xq##k##_0=xpp_[l]; xq##k##_1=xpp_[64+l]; xq##k##_2=xpp_[128+l]; xq##k##_3=xpp_[192+l]; \
    } \
    float a0=quad_add(DOTP(0)); \
    float a1=quad_add(DOTP(1)); \
    float a2=quad_add(DOTP(2)); \
    float a3=quad_add(DOTP(3)); \
    const float gi=a0+cx0, gf=a1+cx1, gg=a2+cx2, go=a3+cx3; \
    c = sig_(gf)*c + sig_(gi)*tanhf_(gg); \
    const float hn = sig_(go)*tanhf_(c); \
    if(q==0) s_h[cur^1][l]=hn; \
    cur^=1; \
    __syncthreads(); \
  }

__global__ __attribute__((amdgpu_flat_work_group_size(256,256), amdgpu_waves_per_eu(1,1)))
void lstm_k(
    const float* __restrict__ xproj, const float* __restrict__ Whh,
    const float* __restrict__ W1, const float* __restrict__ b1,
    const float* __restrict__ W2, const float* __restrict__ b2,
    float* __restrict__ out)
{
  const int tid=threadIdx.x, l=tid>>2, q=tid&3;
  __shared__ __align__(16) float s_h[2][64];
  __shared__ float s_y[32];

  WDECL(0) WDECL(1) WDECL(2) WDECL(3)
  XQDECL(0) XQDECL(1) XQDECL(2) XQDECL(3)

  float c=0.f;
  if(tid<64){ s_h[0][tid]=0.f; s_h[1][tid]=0.f; }
  __syncthreads();
  int cur=0;
  for(int tb=0;tb<1024;tb+=4){
    STEP(0) STEP(1) STEP(2) STEP(3)
  }
  // MLP head: relu(h@W1+b1)@W2+b2  (final h is in s_h[cur])
  if(tid<32){
    float a=b1[tid];
    #pragma unroll 8
    for(int k=0;k<64;k++) a += s_h[cur][k]*W1[k*32+tid];
    s_y[tid]=fmaxf(a,0.f);
  }
  __syncthreads();
  if(tid==0){
    float a=b2[0];
    #pragma unroll
    for(int j=0;j<32;j++) a += s_y[j]*W2[j];
    out[0]=a;
  }
}

extern "C" void kernel_launch(void* const* d_in, const int* in_sizes, int n_in,
                              void* d_out, int out_size, void* d_ws, size_t ws_size,
                              hipStream_t stream) {
  (void)in_sizes; (void)n_in; (void)out_size; (void)ws_size;
  const float* x    = (const float*)d_in[0];
  const int*   ei   = (const int*)d_in[1];
  const float* ea   = (const float*)d_in[2];
  const float* Wl1  = (const float*)d_in[4];
  const float* bl1  = (const float*)d_in[5];
  const float* Wr1  = (const float*)d_in[6];
  const float* br1  = (const float*)d_in[7];
  const float* We1  = (const float*)d_in[8];
  const float* att1 = (const float*)d_in[9];
  const float* bias1= (const float*)d_in[10];
  const float* Wl2  = (const float*)d_in[11];
  const float* bl2  = (const float*)d_in[12];
  const float* Wr2  = (const float*)d_in[13];
  const float* br2  = (const float*)d_in[14];
  const float* We2  = (const float*)d_in[15];
  const float* att2 = (const float*)d_in[16];
  const float* bias2= (const float*)d_in[17];
  const float* Wih  = (const float*)d_in[18];
  const float* Whh  = (const float*)d_in[19];
  const float* bih  = (const float*)d_in[20];
  const float* bhh  = (const float*)d_in[21];
  const float* W1   = (const float*)d_in[22];
  const float* b1   = (const float*)d_in[23];
  const float* W2   = (const float*)d_in[24];
  const float* b2   = (const float*)d_in[25];

  float* h1w = (float*)d_ws;                                  // 65536*192*4 = 50331648 B
  float* xpw = (float*)((char*)d_ws + (size_t)50331648);      // 1024*256*4  = 1048576 B
  float* outp = (float*)d_out;

  gat1_k<<<dim3(SGR), dim3(512), 0, stream>>>(x, ei, ea, Wl1, bl1, Wr1, br1, We1, att1, bias1, h1w);
  gat2_k<<<dim3(SGR), dim3(512), 0, stream>>>(h1w, ei, ea, Wl2, bl2, Wr2, br2, We2, att2, bias2,
                                              Wih, bih, bhh, xpw);
  lstm_k<<<dim3(1), dim3(256), 0, stream>>>(xpw, Whh, W1, b1, W2, b2, outp);
}